// Round 4
// baseline (2299.242 us; speedup 1.0000x reference)
//
#include <hip/hip_runtime.h>
#include <hip/hip_bf16.h>

namespace {

typedef __attribute__((ext_vector_type(8))) short short8x;
typedef __attribute__((ext_vector_type(4))) float f32x4;

__device__ __forceinline__ float bf2f(unsigned short h) {
    return __uint_as_float(((unsigned int)h) << 16);
}
__device__ __forceinline__ unsigned short f2bf(float f) {
    __hip_bfloat16 h = __float2bfloat16(f);
    return *reinterpret_cast<unsigned short*>(&h);
}

enum { ACT_NONE = 0, ACT_TANH = 1 };
enum { EPI_NONE = 0, EPI_KSCALE = 1, EPI_ADDVEC = 2 };

// ---------------- bf16 MFMA GEMM: C[m,n] = sum_k A[m,k]*B[n,k] -----------------
// A: M x K bf16 row-major (M=16384). B: Npad x K bf16 row-major (padded w/ zeros).
// 128x128 tile, 256 threads (4 waves, 2x2 of 64x64), BK=32, one 16x16x32 MFMA
// per 16x16 tile per k-iter. LDS XOR-swizzled (chunk ^= (row>>1)&3) -> 2-way max.
template <int ACT, int EPI, int SBF>
__launch_bounds__(256) __global__
void gemm_mfma(int Npad, int K, int Nreal, int Cstride,
               const unsigned short* __restrict__ A,
               const unsigned short* __restrict__ B,
               float* __restrict__ Cf, unsigned short* __restrict__ Cb,
               const float* __restrict__ epi)
{
    __shared__ unsigned short as_[128 * 32];
    __shared__ unsigned short bs_[128 * 32];
    const int tid = threadIdx.x;
    const int lane = tid & 63;
    const int wave = tid >> 6;
    const int m0 = blockIdx.y << 7;
    const int n0 = blockIdx.x << 7;
    const int wm = (wave >> 1) << 6;
    const int wn = (wave & 1) << 6;

    f32x4 acc[4][4];
    const f32x4 zero = {0.f, 0.f, 0.f, 0.f};
#pragma unroll
    for (int i = 0; i < 4; ++i)
#pragma unroll
        for (int j = 0; j < 4; ++j) acc[i][j] = zero;

    const int sr = tid >> 2;       // row within 64-row chunk
    const int sc4 = tid & 3;       // 8-elt chunk within 32-wide row

    for (int k0 = 0; k0 < K; k0 += 32) {
        const uint4 a0 = *(const uint4*)(A + (size_t)(m0 + sr) * K + k0 + sc4 * 8);
        const uint4 a1 = *(const uint4*)(A + (size_t)(m0 + 64 + sr) * K + k0 + sc4 * 8);
        const uint4 b0 = *(const uint4*)(B + (size_t)(n0 + sr) * K + k0 + sc4 * 8);
        const uint4 b1 = *(const uint4*)(B + (size_t)(n0 + 64 + sr) * K + k0 + sc4 * 8);
        __syncthreads();  // previous iter's LDS reads done
        {
            int r = sr, p = sc4 ^ ((r >> 1) & 3);
            *(uint4*)&as_[r * 32 + p * 8] = a0;
            *(uint4*)&bs_[r * 32 + p * 8] = b0;
            r = 64 + sr; p = sc4 ^ ((r >> 1) & 3);
            *(uint4*)&as_[r * 32 + p * 8] = a1;
            *(uint4*)&bs_[r * 32 + p * 8] = b1;
        }
        __syncthreads();
        const int q = lane >> 4;
        const int l15 = lane & 15;
        short8x af[4], bfr[4];
#pragma unroll
        for (int i = 0; i < 4; ++i) {
            const int m = wm + (i << 4) + l15;
            const int pa = q ^ ((m >> 1) & 3);
            af[i] = *(const short8x*)&as_[m * 32 + pa * 8];
            const int n = wn + (i << 4) + l15;
            const int pb = q ^ ((n >> 1) & 3);
            bfr[i] = *(const short8x*)&bs_[n * 32 + pb * 8];
        }
#pragma unroll
        for (int i = 0; i < 4; ++i)
#pragma unroll
            for (int j = 0; j < 4; ++j)
                acc[i][j] = __builtin_amdgcn_mfma_f32_16x16x32_bf16(af[i], bfr[j], acc[i][j], 0, 0, 0);
    }

    const int q = lane >> 4;
    const int cn = lane & 15;
#pragma unroll
    for (int i = 0; i < 4; ++i) {
#pragma unroll
        for (int j = 0; j < 4; ++j) {
#pragma unroll
            for (int rr = 0; rr < 4; ++rr) {
                const int row = m0 + wm + (i << 4) + (q << 2) + rr;
                const int col = n0 + wn + (j << 4) + cn;
                if (col >= Nreal) continue;
                float v = acc[i][j][rr];
                if constexpr (ACT == ACT_TANH) v = tanhf(v);
                if constexpr (EPI == EPI_KSCALE)
                    v *= __expf(fminf(epi[(size_t)row * 1024 + col], 0.f));
                if constexpr (EPI == EPI_ADDVEC) v += epi[col];
                if constexpr (SBF) Cb[(size_t)row * Cstride + col] = f2bf(v);
                else               Cf[(size_t)row * Cstride + col] = v;
            }
        }
    }
}

// mix[m,c] = bf16(x + (x_last - x) * miu_x[c])
__launch_bounds__(256) __global__
void mix_k(const float* __restrict__ x, const float* __restrict__ xla,
           const float* __restrict__ mux, unsigned short* __restrict__ out)
{
    const size_t idx = ((size_t)blockIdx.x * 256 + threadIdx.x) * 4;
    const int c = (int)(idx & 1023);
    const float4 xv = *(const float4*)(x + idx);
    const float4 xl = *(const float4*)(xla + idx);
    const float4 mu = *(const float4*)(mux + c);
    ushort4 o;
    o.x = f2bf(xv.x + (xl.x - xv.x) * mu.x);
    o.y = f2bf(xv.y + (xl.y - xv.y) * mu.y);
    o.z = f2bf(xv.z + (xl.z - xv.z) * mu.z);
    o.w = f2bf(xv.w + (xl.w - xv.w) * mu.w);
    *(ushort4*)(out + idx) = o;
}

// plain fp32 -> bf16 convert (n mult of 1024; grid = n/1024)
__launch_bounds__(256) __global__
void convert_k(const float* __restrict__ src, unsigned short* __restrict__ dst)
{
    const size_t idx = ((size_t)blockIdx.x * 256 + threadIdx.x) * 4;
    const float4 v = *(const float4*)(src + idx);
    ushort4 o;
    o.x = f2bf(v.x); o.y = f2bf(v.y); o.z = f2bf(v.z); o.w = f2bf(v.w);
    *(ushort4*)(dst + idx) = o;
}

// dst[n*K + k] = (n < Nsrc) ? bf16(src[k*Nsrc + n]) : 0   (grid.y = Npad rows)
__launch_bounds__(256) __global__
void transpose_k(const float* __restrict__ src, unsigned short* __restrict__ dst,
                 int K, int Nsrc)
{
    const int k = blockIdx.x * 256 + threadIdx.x;
    const int n = blockIdx.y;
    if (k < K)
        dst[(size_t)n * K + k] = (n < Nsrc) ? f2bf(src[(size_t)k * Nsrc + n]) : (unsigned short)0;
}

// xdd[f][m,c] = x + (x_last-x) * (lambda[f,c] + sum_kk t1flat[f*524288+m*32+kk]*B_lora[f,kk,c])
__launch_bounds__(256) __global__
void xdd_k(const float* __restrict__ x, const float* __restrict__ xla,
           const unsigned short* __restrict__ t1, const float* __restrict__ blora,
           const float* __restrict__ lam, unsigned short* __restrict__ out, int f)
{
    __shared__ float sh[4][32];
    const int tid = threadIdx.x;
    const int m0 = blockIdx.x << 2;
    if (tid < 128) {
        const int r = tid >> 5, kk = tid & 31;
        sh[r][kk] = bf2f(t1[(size_t)f * 524288 + (size_t)(m0 + r) * 32 + kk]);
    }
    __syncthreads();
    const int c0 = tid << 2;
    const float* bl = blora + f * 32768 + c0;
    float dot[4][4];
#pragma unroll
    for (int r = 0; r < 4; ++r)
#pragma unroll
        for (int j = 0; j < 4; ++j) dot[r][j] = 0.f;
    for (int kk = 0; kk < 32; ++kk) {
        const float4 b4 = *(const float4*)(bl + (size_t)kk * 1024);
#pragma unroll
        for (int r = 0; r < 4; ++r) {
            const float tv = sh[r][kk];
            dot[r][0] = fmaf(tv, b4.x, dot[r][0]);
            dot[r][1] = fmaf(tv, b4.y, dot[r][1]);
            dot[r][2] = fmaf(tv, b4.z, dot[r][2]);
            dot[r][3] = fmaf(tv, b4.w, dot[r][3]);
        }
    }
    const float4 l4 = *(const float4*)(lam + f * 1024 + c0);
#pragma unroll
    for (int r = 0; r < 4; ++r) {
        const size_t idx = (size_t)(m0 + r) * 1024 + c0;
        const float4 xv = *(const float4*)(x + idx);
        const float4 xl = *(const float4*)(xla + idx);
        ushort4 o;
        o.x = f2bf(xv.x + (xl.x - xv.x) * (l4.x + dot[r][0]));
        o.y = f2bf(xv.y + (xl.y - xv.y) * (l4.y + dot[r][1]));
        o.z = f2bf(xv.z + (xl.z - xv.z) * (l4.z + dot[r][2]));
        o.w = f2bf(xv.w + (xl.w - xv.w) * (l4.w + dot[r][3]));
        *(ushort4*)(out + idx) = o;
    }
}

// zero-fill (float4 granularity)
__launch_bounds__(256) __global__
void zero_k(float4* __restrict__ p)
{
    const float4 z = {0.f, 0.f, 0.f, 0.f};
    p[(size_t)blockIdx.x * 256 + threadIdx.x] = z;
}

// in-place decay: p = exp(-exp(p))  (16M elems, grid 16384)
__launch_bounds__(256) __global__
void decay_k(float* __restrict__ p)
{
    const size_t idx = ((size_t)blockIdx.x * 256 + threadIdx.x) * 4;
    const float4 v = *(const float4*)(p + idx);
    float4 o;
    o.x = __expf(-__expf(v.x));
    o.y = __expf(-__expf(v.y));
    o.z = __expf(-__expf(v.z));
    o.w = __expf(-__expf(v.w));
    *(float4*)(p + idx) = o;
}

// WKV6 scan, uniform-load edition. Block = (bh, j-chunk of 8 rows): one wave.
// Lane l = value column i. The block's 8 j-channels' r/k (bf16, 16B) and
// pre-computed decay d (fp32, 32B) per step are WAVE-UNIFORM loads straight
// into registers -- no LDS, no shfl, no readlane, no barriers. Per step per
// lane: shared t = k_j*v_i, then y += r_j*(s_j + u_j*t); s_j = d_j*s_j + t.
// 4-step chunks, A/B double-buffered. Partial y accumulated with native fp32
// global atomics into zeroed y. Block mapping bh = blk&127 keeps all 8
// j-chunks of a bh on the SAME XCD (blk mod 8 equal) -> v reads L2-shared,
// y atomics coalesce in one local L2.
#define BF_LO(x) __uint_as_float((x) << 16)
#define BF_HI(x) __uint_as_float((x) & 0xFFFF0000u)

#define WKV_LOAD(RV, KV, DV, VVv, T0)                                         \
    do {                                                                      \
        _Pragma("unroll")                                                     \
        for (int tt = 0; tt < 4; ++tt) {                                      \
            const size_t o_ = (size_t)((T0) + tt) * 1024;                     \
            RV[tt] = *(const uint4*)(rp + o_);                                \
            KV[tt] = *(const uint4*)(kp + o_);                                \
            DV[tt][0] = *(const float4*)(dp + o_);                            \
            DV[tt][1] = *(const float4*)(dp + o_ + 4);                        \
            VVv[tt] = vp[o_];                                                 \
        }                                                                     \
    } while (0)

#define WKV_PROC(RV, KV, DV, VVv, T0)                                         \
    do {                                                                      \
        _Pragma("unroll")                                                     \
        for (int tt = 0; tt < 4; ++tt) {                                      \
            const float vi_ = bf2f(VVv[tt]);                                  \
            float rj[8], kj[8], dj[8];                                        \
            rj[0] = BF_LO(RV[tt].x); rj[1] = BF_HI(RV[tt].x);                 \
            rj[2] = BF_LO(RV[tt].y); rj[3] = BF_HI(RV[tt].y);                 \
            rj[4] = BF_LO(RV[tt].z); rj[5] = BF_HI(RV[tt].z);                 \
            rj[6] = BF_LO(RV[tt].w); rj[7] = BF_HI(RV[tt].w);                 \
            kj[0] = BF_LO(KV[tt].x); kj[1] = BF_HI(KV[tt].x);                 \
            kj[2] = BF_LO(KV[tt].y); kj[3] = BF_HI(KV[tt].y);                 \
            kj[4] = BF_LO(KV[tt].z); kj[5] = BF_HI(KV[tt].z);                 \
            kj[6] = BF_LO(KV[tt].w); kj[7] = BF_HI(KV[tt].w);                 \
            dj[0] = DV[tt][0].x; dj[1] = DV[tt][0].y;                         \
            dj[2] = DV[tt][0].z; dj[3] = DV[tt][0].w;                         \
            dj[4] = DV[tt][1].x; dj[5] = DV[tt][1].y;                         \
            dj[6] = DV[tt][1].z; dj[7] = DV[tt][1].w;                         \
            float ya0_ = 0.f, ya1_ = 0.f;                                     \
            _Pragma("unroll")                                                 \
            for (int jj = 0; jj < 8; ++jj) {                                  \
                const float t_ = kj[jj] * vi_;                                \
                const float a_ = fmaf(u8[jj], t_, s[jj]);                     \
                if (jj & 1) ya1_ = fmaf(rj[jj], a_, ya1_);                    \
                else        ya0_ = fmaf(rj[jj], a_, ya0_);                    \
                s[jj] = fmaf(dj[jj], s[jj], t_);                              \
            }                                                                 \
            unsafeAtomicAdd(yp + (size_t)((T0) + tt) * 1024, ya0_ + ya1_);    \
        }                                                                     \
    } while (0)

__launch_bounds__(64) __global__
void wkv_k(const unsigned short* __restrict__ r, const unsigned short* __restrict__ k,
           const unsigned short* __restrict__ v, const float* __restrict__ d,
           const float* __restrict__ u, const float* __restrict__ s_in,
           float* __restrict__ y, float* __restrict__ s_out)
{
    const int blk = blockIdx.x;
    const int bh = blk & 127;      // same-bh blocks all == bh (mod 8) -> same XCD
    const int jc = blk >> 7;       // j-chunk (8 rows each)
    const int h = bh & 15;
    const int l = threadIdx.x;
    const int jbase = jc << 3;

    float s[8];
    const size_t sb = (size_t)bh * 4096;
#pragma unroll
    for (int jj = 0; jj < 8; ++jj) s[jj] = s_in[sb + (size_t)(jbase + jj) * 64 + l];

    float u8[8];
#pragma unroll
    for (int jj = 0; jj < 8; ++jj) u8[jj] = u[(h << 6) + jbase + jj];

    const size_t base = (size_t)(bh >> 4) * (2048 * 1024) + (h << 6);
    const unsigned short* rp = r + base + jbase;   // uniform: 8 bf16 per step
    const unsigned short* kp = k + base + jbase;   // uniform
    const float*          dp = d + base + jbase;   // uniform: 8 fp32 per step
    const unsigned short* vp = v + base + l;       // per-lane value column
    float*                yp = y + base + l;       // per-lane output column

    uint4 rA[4], kA[4]; float4 dA[4][2]; unsigned short vA[4];
    uint4 rB[4], kB[4]; float4 dB[4][2]; unsigned short vB[4];

    WKV_LOAD(rA, kA, dA, vA, 0);
    for (int c = 0; c < 512; c += 2) {
        WKV_LOAD(rB, kB, dB, vB, (c + 1) * 4);
        WKV_PROC(rA, kA, dA, vA, c * 4);
        if (c + 2 < 512) WKV_LOAD(rA, kA, dA, vA, (c + 2) * 4);
        WKV_PROC(rB, kB, dB, vB, (c + 1) * 4);
    }
#pragma unroll
    for (int jj = 0; jj < 8; ++jj) s_out[sb + (size_t)(jbase + jj) * 64 + l] = s[jj];
}

// GroupNorm over heads of 64 ch (eps = 1e-5*16), then *g, store bf16 z.
__launch_bounds__(256) __global__
void gn_k(const float* __restrict__ y0,
          const unsigned short* __restrict__ g, const float* __restrict__ gam,
          const float* __restrict__ bet, unsigned short* __restrict__ z)
{
    const int tid = threadIdx.x;
    const size_t row = blockIdx.x;
    const int c0 = tid << 2;
    const size_t idx = row * 1024 + c0;
    const float4 a = *(const float4*)(y0 + idx);
    const float yv0 = a.x, yv1 = a.y, yv2 = a.z, yv3 = a.w;
    float sm = yv0 + yv1 + yv2 + yv3;
    float q = yv0 * yv0 + yv1 * yv1 + yv2 * yv2 + yv3 * yv3;
#pragma unroll
    for (int off = 1; off < 16; off <<= 1) {
        sm += __shfl_xor(sm, off, 64);
        q += __shfl_xor(q, off, 64);
    }
    const float mean = sm * (1.f / 64.f);
    const float var = q * (1.f / 64.f) - mean * mean;
    const float rstd = rsqrtf(var + 1.6e-4f);
    const float4 gm = *(const float4*)(gam + c0);
    const float4 bt = *(const float4*)(bet + c0);
    const ushort4 gg = *(const ushort4*)(g + idx);
    ushort4 o;
    o.x = f2bf(((yv0 - mean) * rstd * gm.x + bt.x) * bf2f(gg.x));
    o.y = f2bf(((yv1 - mean) * rstd * gm.y + bt.y) * bf2f(gg.y));
    o.z = f2bf(((yv2 - mean) * rstd * gm.z + bt.z) * bf2f(gg.z));
    o.w = f2bf(((yv3 - mean) * rstd * gm.w + bt.w) * bf2f(gg.w));
    *(ushort4*)(z + idx) = o;
}

__launch_bounds__(256) __global__
void copy_k(const float4* __restrict__ src, float4* __restrict__ dst)
{
    const size_t i = (size_t)blockIdx.x * 256 + threadIdx.x;
    dst[i] = src[i];
}

}  // namespace

extern "C" void kernel_launch(void* const* d_in, const int* in_sizes, int n_in,
                              void* d_out, int out_size, void* d_ws, size_t ws_size,
                              hipStream_t stream)
{
    (void)in_sizes; (void)n_in; (void)out_size; (void)ws_size;
    const float* x     = (const float*)d_in[0];
    const float* xla   = (const float*)d_in[1];
    const float* s_in  = (const float*)d_in[2];
    const float* mux   = (const float*)d_in[3];
    const float* lam   = (const float*)d_in[4];
    const float* Amat  = (const float*)d_in[5];
    const float* blora = (const float*)d_in[6];
    const float* tdmu  = (const float*)d_in[7];
    const float* tdA   = (const float*)d_in[8];
    const float* tdB   = (const float*)d_in[9];
    const float* u     = (const float*)d_in[10];
    const float* Wk    = (const float*)d_in[11];
    const float* Wv    = (const float*)d_in[12];
    const float* Wr    = (const float*)d_in[13];
    const float* Wo    = (const float*)d_in[14];
    const float* Wg1   = (const float*)d_in[15];
    const float* Wg2   = (const float*)d_in[16];
    const float* gam   = (const float*)d_in[17];
    const float* bet   = (const float*)d_in[18];

    float* out  = (float*)d_out;          // w-scratch until final GEMM
    float* xraw = out + 16777216;         // y0 scratch until final copy
    float* snew = out + 2 * 16777216;

    char* ws = (char*)d_ws;
    unsigned short* mixb   = (unsigned short*)(ws);              // 32 MB (dead after G1)
    unsigned short* xddb   = (unsigned short*)(ws + 33554432);   // 32 MB (dead after G7)
    unsigned short* t1     = (unsigned short*)(ws + 67108864);   // 5.25 MB
    unsigned short* tanh64 = (unsigned short*)(ws + 72351744);   // 2 MB
    unsigned short* tanhg  = (unsigned short*)(ws + 74448896);   // 5.25 MB
    unsigned short* kbuf   = (unsigned short*)(ws + 79691776);   // 32 MB (-> z after wkv)
    unsigned short* vbuf   = (unsigned short*)(ws + 113246208);  // 32 MB
    unsigned short* rbuf   = (unsigned short*)(ws + 146800640);  // 32 MB
    unsigned short* gbuf   = (unsigned short*)(ws + 180355072);  // 32 MB
    unsigned short* wkt    = (unsigned short*)(ws + 213909504);  // 2 MB
    unsigned short* wvt    = (unsigned short*)(ws + 216006656);
    unsigned short* wrt    = (unsigned short*)(ws + 218103808);
    unsigned short* wot    = (unsigned short*)(ws + 220200960);
    unsigned short* at_    = (unsigned short*)(ws + 222298112);  // 256x1024
    unsigned short* tdat   = (unsigned short*)(ws + 222822400);  // 128x1024
    unsigned short* tdbt   = (unsigned short*)(ws + 223084544);  // 1024x64
    unsigned short* wg1t   = (unsigned short*)(ws + 223215616);  // 256x1024
    unsigned short* wg2t   = (unsigned short*)(ws + 223739904);  // 1024x160 (end ~224 MB)

    float* w  = out;            // 16384x1024 fp32 (becomes decay d in-place)
    float* y0 = xraw;           // fp32 y accumulator (atomic)

    // --- weight conversions ---
    convert_k<<<1024, 256, 0, stream>>>(Wk, wkt);
    convert_k<<<1024, 256, 0, stream>>>(Wv, wvt);
    convert_k<<<1024, 256, 0, stream>>>(Wr, wrt);
    convert_k<<<1024, 256, 0, stream>>>(Wo, wot);
    transpose_k<<<dim3(4, 256), 256, 0, stream>>>(Amat, at_, 1024, 160);
    transpose_k<<<dim3(4, 128), 256, 0, stream>>>(tdA, tdat, 1024, 64);
    transpose_k<<<dim3(1, 1024), 256, 0, stream>>>(tdB, tdbt, 64, 1024);
    transpose_k<<<dim3(4, 256), 256, 0, stream>>>(Wg1, wg1t, 1024, 160);
    transpose_k<<<dim3(1, 1024), 256, 0, stream>>>(Wg2, wg2t, 160, 1024);

    // --- G1: t1 = tanh(mix @ A)  (N=160 pad 256, K=1024) ---
    mix_k<<<16384, 256, 0, stream>>>(x, xla, mux, mixb);
    gemm_mfma<ACT_TANH, EPI_NONE, 1><<<dim3(2, 128), 256, 0, stream>>>(
        256, 1024, 160, 160, mixb, at_, nullptr, t1, nullptr);

    // --- f=0: w = tdmu + tanh(w0 @ tdA) @ tdB ---
    xdd_k<<<4096, 256, 0, stream>>>(x, xla, t1, blora, lam, xddb, 0);
    gemm_mfma<ACT_TANH, EPI_NONE, 1><<<dim3(1, 128), 256, 0, stream>>>(
        128, 1024, 64, 64, xddb, tdat, nullptr, tanh64, nullptr);
    gemm_mfma<ACT_NONE, EPI_ADDVEC, 0><<<dim3(8, 128), 256, 0, stream>>>(
        1024, 64, 1024, 1024, tanh64, tdbt, w, nullptr, tdmu);

    // --- f=1: k = (k0 @ Wk^T) * exp(min(w,0)) -> bf16 ---
    xdd_k<<<4096, 256, 0, stream>>>(x, xla, t1, blora, lam, xddb, 1);
    gemm_mfma<ACT_NONE, EPI_KSCALE, 1><<<dim3(8, 128), 256, 0, stream>>>(
        1024, 1024, 1024, 1024, xddb, wkt, nullptr, kbuf, w);

    // --- w -> d = exp(-exp(w)) in place (raw w no longer needed) ---
    decay_k<<<16384, 256, 0, stream>>>(w);

    // --- f=2: v ---
    xdd_k<<<4096, 256, 0, stream>>>(x, xla, t1, blora, lam, xddb, 2);
    gemm_mfma<ACT_NONE, EPI_NONE, 1><<<dim3(8, 128), 256, 0, stream>>>(
        1024, 1024, 1024, 1024, xddb, wvt, nullptr, vbuf, nullptr);

    // --- f=3: r ---
    xdd_k<<<4096, 256, 0, stream>>>(x, xla, t1, blora, lam, xddb, 3);
    gemm_mfma<ACT_NONE, EPI_NONE, 1><<<dim3(8, 128), 256, 0, stream>>>(
        1024, 1024, 1024, 1024, xddb, wrt, nullptr, rbuf, nullptr);

    // --- f=4: g = tanh(g0 @ Wg1) @ Wg2 ---
    xdd_k<<<4096, 256, 0, stream>>>(x, xla, t1, blora, lam, xddb, 4);
    gemm_mfma<ACT_TANH, EPI_NONE, 1><<<dim3(2, 128), 256, 0, stream>>>(
        256, 1024, 160, 160, xddb, wg1t, nullptr, tanhg, nullptr);
    gemm_mfma<ACT_NONE, EPI_NONE, 1><<<dim3(8, 128), 256, 0, stream>>>(
        1024, 160, 1024, 1024, tanhg, wg2t, nullptr, gbuf, nullptr);

    // --- WKV scan (8 j-chunks per bh, same-XCD, atomic partial-y into zeroed y0) ---
    zero_k<<<16384, 256, 0, stream>>>((float4*)y0);
    wkv_k<<<1024, 64, 0, stream>>>(rbuf, kbuf, vbuf, w, u, s_in, y0, snew);

    // --- GroupNorm(y0)*g -> z (reuses kbuf) ---
    gn_k<<<16384, 256, 0, stream>>>(y0, gbuf, gam, bet, kbuf);

    // --- out = z @ Wo^T (fp32, overwrites w scratch) ---
    gemm_mfma<ACT_NONE, EPI_NONE, 0><<<dim3(8, 128), 256, 0, stream>>>(
        1024, 1024, 1024, 1024, kbuf, wot, out, nullptr, nullptr);

    // --- x_raw = x ---
    copy_k<<<16384, 256, 0, stream>>>((const float4*)x, (float4*)xraw);
}

// Round 5
// 1675.793 us; speedup vs baseline: 1.3720x; 1.3720x over previous
//
#include <hip/hip_runtime.h>
#include <hip/hip_bf16.h>

namespace {

typedef __attribute__((ext_vector_type(8))) short short8x;
typedef __attribute__((ext_vector_type(4))) float f32x4;

__device__ __forceinline__ float bf2f(unsigned short h) {
    return __uint_as_float(((unsigned int)h) << 16);
}
__device__ __forceinline__ unsigned short f2bf(float f) {
    __hip_bfloat16 h = __float2bfloat16(f);
    return *reinterpret_cast<unsigned short*>(&h);
}

enum { ACT_NONE = 0, ACT_TANH = 1 };
enum { EPI_NONE = 0, EPI_KSCALE = 1, EPI_ADDVEC = 2 };

// ---------------- bf16 MFMA GEMM: C[m,n] = sum_k A[m,k]*B[n,k] -----------------
// A: M x K bf16 row-major (M=16384). B: Npad x K bf16 row-major (padded w/ zeros).
// 128x128 tile, 256 threads (4 waves, 2x2 of 64x64), BK=32, one 16x16x32 MFMA
// per 16x16 tile per k-iter. LDS XOR-swizzled (chunk ^= (row>>1)&3) -> 2-way max.
template <int ACT, int EPI, int SBF>
__launch_bounds__(256) __global__
void gemm_mfma(int Npad, int K, int Nreal, int Cstride,
               const unsigned short* __restrict__ A,
               const unsigned short* __restrict__ B,
               float* __restrict__ Cf, unsigned short* __restrict__ Cb,
               const float* __restrict__ epi)
{
    __shared__ unsigned short as_[128 * 32];
    __shared__ unsigned short bs_[128 * 32];
    const int tid = threadIdx.x;
    const int lane = tid & 63;
    const int wave = tid >> 6;
    const int m0 = blockIdx.y << 7;
    const int n0 = blockIdx.x << 7;
    const int wm = (wave >> 1) << 6;
    const int wn = (wave & 1) << 6;

    f32x4 acc[4][4];
    const f32x4 zero = {0.f, 0.f, 0.f, 0.f};
#pragma unroll
    for (int i = 0; i < 4; ++i)
#pragma unroll
        for (int j = 0; j < 4; ++j) acc[i][j] = zero;

    const int sr = tid >> 2;       // row within 64-row chunk
    const int sc4 = tid & 3;       // 8-elt chunk within 32-wide row

    for (int k0 = 0; k0 < K; k0 += 32) {
        const uint4 a0 = *(const uint4*)(A + (size_t)(m0 + sr) * K + k0 + sc4 * 8);
        const uint4 a1 = *(const uint4*)(A + (size_t)(m0 + 64 + sr) * K + k0 + sc4 * 8);
        const uint4 b0 = *(const uint4*)(B + (size_t)(n0 + sr) * K + k0 + sc4 * 8);
        const uint4 b1 = *(const uint4*)(B + (size_t)(n0 + 64 + sr) * K + k0 + sc4 * 8);
        __syncthreads();  // previous iter's LDS reads done
        {
            int r = sr, p = sc4 ^ ((r >> 1) & 3);
            *(uint4*)&as_[r * 32 + p * 8] = a0;
            *(uint4*)&bs_[r * 32 + p * 8] = b0;
            r = 64 + sr; p = sc4 ^ ((r >> 1) & 3);
            *(uint4*)&as_[r * 32 + p * 8] = a1;
            *(uint4*)&bs_[r * 32 + p * 8] = b1;
        }
        __syncthreads();
        const int q = lane >> 4;
        const int l15 = lane & 15;
        short8x af[4], bfr[4];
#pragma unroll
        for (int i = 0; i < 4; ++i) {
            const int m = wm + (i << 4) + l15;
            const int pa = q ^ ((m >> 1) & 3);
            af[i] = *(const short8x*)&as_[m * 32 + pa * 8];
            const int n = wn + (i << 4) + l15;
            const int pb = q ^ ((n >> 1) & 3);
            bfr[i] = *(const short8x*)&bs_[n * 32 + pb * 8];
        }
#pragma unroll
        for (int i = 0; i < 4; ++i)
#pragma unroll
            for (int j = 0; j < 4; ++j)
                acc[i][j] = __builtin_amdgcn_mfma_f32_16x16x32_bf16(af[i], bfr[j], acc[i][j], 0, 0, 0);
    }

    const int q = lane >> 4;
    const int cn = lane & 15;
#pragma unroll
    for (int i = 0; i < 4; ++i) {
#pragma unroll
        for (int j = 0; j < 4; ++j) {
#pragma unroll
            for (int rr = 0; rr < 4; ++rr) {
                const int row = m0 + wm + (i << 4) + (q << 2) + rr;
                const int col = n0 + wn + (j << 4) + cn;
                if (col >= Nreal) continue;
                float v = acc[i][j][rr];
                if constexpr (ACT == ACT_TANH) v = tanhf(v);
                if constexpr (EPI == EPI_KSCALE)
                    v *= __expf(fminf(epi[(size_t)row * 1024 + col], 0.f));
                if constexpr (EPI == EPI_ADDVEC) v += epi[col];
                if constexpr (SBF) Cb[(size_t)row * Cstride + col] = f2bf(v);
                else               Cf[(size_t)row * Cstride + col] = v;
            }
        }
    }
}

// mix[m,c] = bf16(x + (x_last - x) * miu_x[c])
__launch_bounds__(256) __global__
void mix_k(const float* __restrict__ x, const float* __restrict__ xla,
           const float* __restrict__ mux, unsigned short* __restrict__ out)
{
    const size_t idx = ((size_t)blockIdx.x * 256 + threadIdx.x) * 4;
    const int c = (int)(idx & 1023);
    const float4 xv = *(const float4*)(x + idx);
    const float4 xl = *(const float4*)(xla + idx);
    const float4 mu = *(const float4*)(mux + c);
    ushort4 o;
    o.x = f2bf(xv.x + (xl.x - xv.x) * mu.x);
    o.y = f2bf(xv.y + (xl.y - xv.y) * mu.y);
    o.z = f2bf(xv.z + (xl.z - xv.z) * mu.z);
    o.w = f2bf(xv.w + (xl.w - xv.w) * mu.w);
    *(ushort4*)(out + idx) = o;
}

// plain fp32 -> bf16 convert (n mult of 1024; grid = n/1024)
__launch_bounds__(256) __global__
void convert_k(const float* __restrict__ src, unsigned short* __restrict__ dst)
{
    const size_t idx = ((size_t)blockIdx.x * 256 + threadIdx.x) * 4;
    const float4 v = *(const float4*)(src + idx);
    ushort4 o;
    o.x = f2bf(v.x); o.y = f2bf(v.y); o.z = f2bf(v.z); o.w = f2bf(v.w);
    *(ushort4*)(dst + idx) = o;
}

// dst[n*K + k] = (n < Nsrc) ? bf16(src[k*Nsrc + n]) : 0   (grid.y = Npad rows)
__launch_bounds__(256) __global__
void transpose_k(const float* __restrict__ src, unsigned short* __restrict__ dst,
                 int K, int Nsrc)
{
    const int k = blockIdx.x * 256 + threadIdx.x;
    const int n = blockIdx.y;
    if (k < K)
        dst[(size_t)n * K + k] = (n < Nsrc) ? f2bf(src[(size_t)k * Nsrc + n]) : (unsigned short)0;
}

// xdd[f][m,c] = x + (x_last-x) * (lambda[f,c] + sum_kk t1flat[f*524288+m*32+kk]*B_lora[f,kk,c])
__launch_bounds__(256) __global__
void xdd_k(const float* __restrict__ x, const float* __restrict__ xla,
           const unsigned short* __restrict__ t1, const float* __restrict__ blora,
           const float* __restrict__ lam, unsigned short* __restrict__ out, int f)
{
    __shared__ float sh[4][32];
    const int tid = threadIdx.x;
    const int m0 = blockIdx.x << 2;
    if (tid < 128) {
        const int r = tid >> 5, kk = tid & 31;
        sh[r][kk] = bf2f(t1[(size_t)f * 524288 + (size_t)(m0 + r) * 32 + kk]);
    }
    __syncthreads();
    const int c0 = tid << 2;
    const float* bl = blora + f * 32768 + c0;
    float dot[4][4];
#pragma unroll
    for (int r = 0; r < 4; ++r)
#pragma unroll
        for (int j = 0; j < 4; ++j) dot[r][j] = 0.f;
    for (int kk = 0; kk < 32; ++kk) {
        const float4 b4 = *(const float4*)(bl + (size_t)kk * 1024);
#pragma unroll
        for (int r = 0; r < 4; ++r) {
            const float tv = sh[r][kk];
            dot[r][0] = fmaf(tv, b4.x, dot[r][0]);
            dot[r][1] = fmaf(tv, b4.y, dot[r][1]);
            dot[r][2] = fmaf(tv, b4.z, dot[r][2]);
            dot[r][3] = fmaf(tv, b4.w, dot[r][3]);
        }
    }
    const float4 l4 = *(const float4*)(lam + f * 1024 + c0);
#pragma unroll
    for (int r = 0; r < 4; ++r) {
        const size_t idx = (size_t)(m0 + r) * 1024 + c0;
        const float4 xv = *(const float4*)(x + idx);
        const float4 xl = *(const float4*)(xla + idx);
        ushort4 o;
        o.x = f2bf(xv.x + (xl.x - xv.x) * (l4.x + dot[r][0]));
        o.y = f2bf(xv.y + (xl.y - xv.y) * (l4.y + dot[r][1]));
        o.z = f2bf(xv.z + (xl.z - xv.z) * (l4.z + dot[r][2]));
        o.w = f2bf(xv.w + (xl.w - xv.w) * (l4.w + dot[r][3]));
        *(ushort4*)(out + idx) = o;
    }
}

// zero-fill (float4 granularity)
__launch_bounds__(256) __global__
void zero_k(float4* __restrict__ p)
{
    const float4 z = {0.f, 0.f, 0.f, 0.f};
    p[(size_t)blockIdx.x * 256 + threadIdx.x] = z;
}

// in-place decay: p = exp(-exp(p))  (16M elems, grid 16384)
__launch_bounds__(256) __global__
void decay_k(float* __restrict__ p)
{
    const size_t idx = ((size_t)blockIdx.x * 256 + threadIdx.x) * 4;
    const float4 v = *(const float4*)(p + idx);
    float4 o;
    o.x = __expf(-__expf(v.x));
    o.y = __expf(-__expf(v.y));
    o.z = __expf(-__expf(v.z));
    o.w = __expf(-__expf(v.w));
    *(float4*)(p + idx) = o;
}

// ---------------- WKV6: chunked-parallel linear scan over T ------------------
// s_t = d_t (*) s_{t-1} + k_t (x) v_t is linear -> split T=2048 into 16 chunks
// of 128. pass1: chunk-local scan (s=0), emits end-state sloc + decay product
// D = prod(d). pass2: tiny sequential combine s_start[c+1] = D[c]*s_start[c]
// + sloc[c]. pass3: the per-chunk scan with the true start state, emitting y.
// 16384 one-wave blocks (pass1/3) = 32 resident waves/CU (36 VGPR) -> load
// latency hidden by TLP (round-4 failure mode: 1 wave/SIMD, 87% stall).
// Block mapping bh = blk&127 keeps the 8 j-chunk writers of each y line and
// the v readers on the SAME XCD (blk mod 8 equal).
#define BF_LO(x) __uint_as_float((x) << 16)
#define BF_HI(x) __uint_as_float((x) & 0xFFFF0000u)

#define WKV_LOAD(RV, KV, DV, VVv, T0)                                         \
    do {                                                                      \
        _Pragma("unroll")                                                     \
        for (int tt = 0; tt < 4; ++tt) {                                      \
            const size_t o_ = (size_t)((T0) + tt) * 1024;                     \
            RV[tt] = *(const uint4*)(rp + o_);                                \
            KV[tt] = *(const uint4*)(kp + o_);                                \
            DV[tt][0] = *(const float4*)(dp + o_);                            \
            DV[tt][1] = *(const float4*)(dp + o_ + 4);                        \
            VVv[tt] = vp[o_];                                                 \
        }                                                                     \
    } while (0)

#define WKV_PROC(RV, KV, DV, VVv, T0)                                         \
    do {                                                                      \
        _Pragma("unroll")                                                     \
        for (int tt = 0; tt < 4; ++tt) {                                      \
            const float vi_ = bf2f(VVv[tt]);                                  \
            float rj[8], kj[8], dj[8];                                        \
            rj[0] = BF_LO(RV[tt].x); rj[1] = BF_HI(RV[tt].x);                 \
            rj[2] = BF_LO(RV[tt].y); rj[3] = BF_HI(RV[tt].y);                 \
            rj[4] = BF_LO(RV[tt].z); rj[5] = BF_HI(RV[tt].z);                 \
            rj[6] = BF_LO(RV[tt].w); rj[7] = BF_HI(RV[tt].w);                 \
            kj[0] = BF_LO(KV[tt].x); kj[1] = BF_HI(KV[tt].x);                 \
            kj[2] = BF_LO(KV[tt].y); kj[3] = BF_HI(KV[tt].y);                 \
            kj[4] = BF_LO(KV[tt].z); kj[5] = BF_HI(KV[tt].z);                 \
            kj[6] = BF_LO(KV[tt].w); kj[7] = BF_HI(KV[tt].w);                 \
            dj[0] = DV[tt][0].x; dj[1] = DV[tt][0].y;                         \
            dj[2] = DV[tt][0].z; dj[3] = DV[tt][0].w;                         \
            dj[4] = DV[tt][1].x; dj[5] = DV[tt][1].y;                         \
            dj[6] = DV[tt][1].z; dj[7] = DV[tt][1].w;                         \
            float ya0_ = 0.f, ya1_ = 0.f;                                     \
            _Pragma("unroll")                                                 \
            for (int jj = 0; jj < 8; ++jj) {                                  \
                const float t_ = kj[jj] * vi_;                                \
                const float a_ = fmaf(u8[jj], t_, s[jj]);                     \
                if (jj & 1) ya1_ = fmaf(rj[jj], a_, ya1_);                    \
                else        ya0_ = fmaf(rj[jj], a_, ya0_);                    \
                s[jj] = fmaf(dj[jj], s[jj], t_);                              \
            }                                                                 \
            unsafeAtomicAdd(yp + (size_t)((T0) + tt) * 1024, ya0_ + ya1_);    \
        }                                                                     \
    } while (0)

#define P1_LOAD(KV, DV, VVv, T0)                                              \
    do {                                                                      \
        _Pragma("unroll")                                                     \
        for (int tt = 0; tt < 4; ++tt) {                                      \
            const size_t o_ = (size_t)((T0) + tt) * 1024;                     \
            KV[tt] = *(const uint4*)(kp + o_);                                \
            DV[tt][0] = *(const float4*)(dp + o_);                            \
            DV[tt][1] = *(const float4*)(dp + o_ + 4);                        \
            VVv[tt] = vp[o_];                                                 \
        }                                                                     \
    } while (0)

#define P1_PROC(KV, DV, VVv)                                                  \
    do {                                                                      \
        _Pragma("unroll")                                                     \
        for (int tt = 0; tt < 4; ++tt) {                                      \
            const float vi_ = bf2f(VVv[tt]);                                  \
            float kj[8], dj[8];                                               \
            kj[0] = BF_LO(KV[tt].x); kj[1] = BF_HI(KV[tt].x);                 \
            kj[2] = BF_LO(KV[tt].y); kj[3] = BF_HI(KV[tt].y);                 \
            kj[4] = BF_LO(KV[tt].z); kj[5] = BF_HI(KV[tt].z);                 \
            kj[6] = BF_LO(KV[tt].w); kj[7] = BF_HI(KV[tt].w);                 \
            dj[0] = DV[tt][0].x; dj[1] = DV[tt][0].y;                         \
            dj[2] = DV[tt][0].z; dj[3] = DV[tt][0].w;                         \
            dj[4] = DV[tt][1].x; dj[5] = DV[tt][1].y;                         \
            dj[6] = DV[tt][1].z; dj[7] = DV[tt][1].w;                         \
            _Pragma("unroll")                                                 \
            for (int jj = 0; jj < 8; ++jj) {                                  \
                const float t_ = kj[jj] * vi_;                                \
                s[jj] = fmaf(dj[jj], s[jj], t_);                              \
                D[jj] *= dj[jj];                                              \
            }                                                                 \
        }                                                                     \
    } while (0)

// pass1: per (bh, t-chunk, j-chunk): local scan (s=0), write sloc + D.
__launch_bounds__(64) __global__
void wkv_p1(const unsigned short* __restrict__ k, const unsigned short* __restrict__ v,
            const float* __restrict__ d,
            float* __restrict__ slocal, float* __restrict__ dprod)
{
    const int blk = blockIdx.x;
    const int bh = blk & 127;
    const int jc = (blk >> 7) & 7;
    const int tc = blk >> 10;
    const int h = bh & 15;
    const int l = threadIdx.x;
    const int jbase = jc << 3;

    float s[8], D[8];
#pragma unroll
    for (int jj = 0; jj < 8; ++jj) { s[jj] = 0.f; D[jj] = 1.f; }

    const size_t base = (size_t)(bh >> 4) * (2048 * 1024) + (size_t)tc * 131072 + (h << 6);
    const unsigned short* kp = k + base + jbase;
    const float*          dp = d + base + jbase;
    const unsigned short* vp = v + base + l;

    uint4 kA[4]; float4 dA[4][2]; unsigned short vA[4];
    uint4 kB[4]; float4 dB[4][2]; unsigned short vB[4];

    P1_LOAD(kA, dA, vA, 0);
    for (int c = 0; c < 32; c += 2) {
        P1_LOAD(kB, dB, vB, (c + 1) * 4);
        P1_PROC(kA, dA, vA);
        if (c + 2 < 32) P1_LOAD(kA, dA, vA, (c + 2) * 4);
        P1_PROC(kB, dB, vB);
    }
    const size_t cb = (size_t)(tc * 128 + bh) * 64 + jbase;
#pragma unroll
    for (int jj = 0; jj < 8; ++jj) slocal[(cb + jj) * 64 + l] = s[jj];
    if (l == 0) {
#pragma unroll
        for (int jj = 0; jj < 8; ++jj) dprod[cb + jj] = D[jj];
    }
}

// pass2: per (bh, j-chunk): sequential combine over 16 chunks.
// sstart[c] = state at chunk start; s_out = state after chunk 15.
__launch_bounds__(64) __global__
void wkv_p2(const float* __restrict__ s_in, const float* __restrict__ slocal,
            const float* __restrict__ dprod, float* __restrict__ sstart,
            float* __restrict__ s_out)
{
    const int blk = blockIdx.x;
    const int bh = blk & 127;
    const int jc = blk >> 7;
    const int l = threadIdx.x;
    const int jbase = jc << 3;

    float s[8];
    const size_t sb = (size_t)bh * 4096;
#pragma unroll
    for (int jj = 0; jj < 8; ++jj) s[jj] = s_in[sb + (size_t)(jbase + jj) * 64 + l];

    for (int c = 0; c < 16; ++c) {
        const size_t cb = (size_t)(c * 128 + bh) * 64 + jbase;
#pragma unroll
        for (int jj = 0; jj < 8; ++jj) sstart[(cb + jj) * 64 + l] = s[jj];
#pragma unroll
        for (int jj = 0; jj < 8; ++jj)
            s[jj] = fmaf(dprod[cb + jj], s[jj], slocal[(cb + jj) * 64 + l]);
    }
#pragma unroll
    for (int jj = 0; jj < 8; ++jj) s_out[sb + (size_t)(jbase + jj) * 64 + l] = s[jj];
}

// pass3: per (bh, t-chunk, j-chunk): true scan from sstart, emit y (atomic).
__launch_bounds__(64) __global__
void wkv_p3(const unsigned short* __restrict__ r, const unsigned short* __restrict__ k,
            const unsigned short* __restrict__ v, const float* __restrict__ d,
            const float* __restrict__ u, const float* __restrict__ sstart,
            float* __restrict__ y)
{
    const int blk = blockIdx.x;
    const int bh = blk & 127;
    const int jc = (blk >> 7) & 7;
    const int tc = blk >> 10;
    const int h = bh & 15;
    const int l = threadIdx.x;
    const int jbase = jc << 3;

    float s[8];
    const size_t cb = (size_t)(tc * 128 + bh) * 64 + jbase;
#pragma unroll
    for (int jj = 0; jj < 8; ++jj) s[jj] = sstart[(cb + jj) * 64 + l];

    float u8[8];
#pragma unroll
    for (int jj = 0; jj < 8; ++jj) u8[jj] = u[(h << 6) + jbase + jj];

    const size_t base = (size_t)(bh >> 4) * (2048 * 1024) + (size_t)tc * 131072 + (h << 6);
    const unsigned short* rp = r + base + jbase;
    const unsigned short* kp = k + base + jbase;
    const float*          dp = d + base + jbase;
    const unsigned short* vp = v + base + l;
    float*                yp = y + base + l;

    uint4 rA[4], kA[4]; float4 dA[4][2]; unsigned short vA[4];
    uint4 rB[4], kB[4]; float4 dB[4][2]; unsigned short vB[4];

    WKV_LOAD(rA, kA, dA, vA, 0);
    for (int c = 0; c < 32; c += 2) {
        WKV_LOAD(rB, kB, dB, vB, (c + 1) * 4);
        WKV_PROC(rA, kA, dA, vA, c * 4);
        if (c + 2 < 32) WKV_LOAD(rA, kA, dA, vA, (c + 2) * 4);
        WKV_PROC(rB, kB, dB, vB, (c + 1) * 4);
    }
}

// GroupNorm over heads of 64 ch (eps = 1e-5*16), then *g, store bf16 z.
__launch_bounds__(256) __global__
void gn_k(const float* __restrict__ y0,
          const unsigned short* __restrict__ g, const float* __restrict__ gam,
          const float* __restrict__ bet, unsigned short* __restrict__ z)
{
    const int tid = threadIdx.x;
    const size_t row = blockIdx.x;
    const int c0 = tid << 2;
    const size_t idx = row * 1024 + c0;
    const float4 a = *(const float4*)(y0 + idx);
    const float yv0 = a.x, yv1 = a.y, yv2 = a.z, yv3 = a.w;
    float sm = yv0 + yv1 + yv2 + yv3;
    float q = yv0 * yv0 + yv1 * yv1 + yv2 * yv2 + yv3 * yv3;
#pragma unroll
    for (int off = 1; off < 16; off <<= 1) {
        sm += __shfl_xor(sm, off, 64);
        q += __shfl_xor(q, off, 64);
    }
    const float mean = sm * (1.f / 64.f);
    const float var = q * (1.f / 64.f) - mean * mean;
    const float rstd = rsqrtf(var + 1.6e-4f);
    const float4 gm = *(const float4*)(gam + c0);
    const float4 bt = *(const float4*)(bet + c0);
    const ushort4 gg = *(const ushort4*)(g + idx);
    ushort4 o;
    o.x = f2bf(((yv0 - mean) * rstd * gm.x + bt.x) * bf2f(gg.x));
    o.y = f2bf(((yv1 - mean) * rstd * gm.y + bt.y) * bf2f(gg.y));
    o.z = f2bf(((yv2 - mean) * rstd * gm.z + bt.z) * bf2f(gg.z));
    o.w = f2bf(((yv3 - mean) * rstd * gm.w + bt.w) * bf2f(gg.w));
    *(ushort4*)(z + idx) = o;
}

__launch_bounds__(256) __global__
void copy_k(const float4* __restrict__ src, float4* __restrict__ dst)
{
    const size_t i = (size_t)blockIdx.x * 256 + threadIdx.x;
    dst[i] = src[i];
}

}  // namespace

extern "C" void kernel_launch(void* const* d_in, const int* in_sizes, int n_in,
                              void* d_out, int out_size, void* d_ws, size_t ws_size,
                              hipStream_t stream)
{
    (void)in_sizes; (void)n_in; (void)out_size; (void)ws_size;
    const float* x     = (const float*)d_in[0];
    const float* xla   = (const float*)d_in[1];
    const float* s_in  = (const float*)d_in[2];
    const float* mux   = (const float*)d_in[3];
    const float* lam   = (const float*)d_in[4];
    const float* Amat  = (const float*)d_in[5];
    const float* blora = (const float*)d_in[6];
    const float* tdmu  = (const float*)d_in[7];
    const float* tdA   = (const float*)d_in[8];
    const float* tdB   = (const float*)d_in[9];
    const float* u     = (const float*)d_in[10];
    const float* Wk    = (const float*)d_in[11];
    const float* Wv    = (const float*)d_in[12];
    const float* Wr    = (const float*)d_in[13];
    const float* Wo    = (const float*)d_in[14];
    const float* Wg1   = (const float*)d_in[15];
    const float* Wg2   = (const float*)d_in[16];
    const float* gam   = (const float*)d_in[17];
    const float* bet   = (const float*)d_in[18];

    float* out  = (float*)d_out;          // w-scratch until final GEMM
    float* xraw = out + 16777216;         // y0 scratch until final copy
    float* snew = out + 2 * 16777216;

    char* ws = (char*)d_ws;
    unsigned short* mixb   = (unsigned short*)(ws);              // 32 MB (dead after G1 -> slocal)
    unsigned short* xddb   = (unsigned short*)(ws + 33554432);   // 32 MB (dead after f=4 gemm -> sstart)
    unsigned short* t1     = (unsigned short*)(ws + 67108864);   // 5.25 MB (dead after f=4 xdd -> dprod)
    unsigned short* tanh64 = (unsigned short*)(ws + 72351744);   // 2 MB
    unsigned short* tanhg  = (unsigned short*)(ws + 74448896);   // 5.25 MB
    unsigned short* kbuf   = (unsigned short*)(ws + 79691776);   // 32 MB (-> z after wkv)
    unsigned short* vbuf   = (unsigned short*)(ws + 113246208);  // 32 MB
    unsigned short* rbuf   = (unsigned short*)(ws + 146800640);  // 32 MB
    unsigned short* gbuf   = (unsigned short*)(ws + 180355072);  // 32 MB
    unsigned short* wkt    = (unsigned short*)(ws + 213909504);  // 2 MB
    unsigned short* wvt    = (unsigned short*)(ws + 216006656);
    unsigned short* wrt    = (unsigned short*)(ws + 218103808);
    unsigned short* wot    = (unsigned short*)(ws + 220200960);
    unsigned short* at_    = (unsigned short*)(ws + 222298112);  // 256x1024
    unsigned short* tdat   = (unsigned short*)(ws + 222822400);  // 128x1024
    unsigned short* tdbt   = (unsigned short*)(ws + 223084544);  // 1024x64
    unsigned short* wg1t   = (unsigned short*)(ws + 223215616);  // 256x1024
    unsigned short* wg2t   = (unsigned short*)(ws + 223739904);  // 1024x160 (end ~224 MB)

    float* w  = out;            // 16384x1024 fp32 (becomes decay d in-place)
    float* y0 = xraw;           // fp32 y accumulator (atomic)
    float* slocal = (float*)ws;               // 32 MB (over dead mixb)
    float* sstart = (float*)(ws + 33554432);  // 32 MB (over dead xddb)
    float* dprod  = (float*)(ws + 67108864);  // 512 KB (over dead t1)

    // --- weight conversions ---
    convert_k<<<1024, 256, 0, stream>>>(Wk, wkt);
    convert_k<<<1024, 256, 0, stream>>>(Wv, wvt);
    convert_k<<<1024, 256, 0, stream>>>(Wr, wrt);
    convert_k<<<1024, 256, 0, stream>>>(Wo, wot);
    transpose_k<<<dim3(4, 256), 256, 0, stream>>>(Amat, at_, 1024, 160);
    transpose_k<<<dim3(4, 128), 256, 0, stream>>>(tdA, tdat, 1024, 64);
    transpose_k<<<dim3(1, 1024), 256, 0, stream>>>(tdB, tdbt, 64, 1024);
    transpose_k<<<dim3(4, 256), 256, 0, stream>>>(Wg1, wg1t, 1024, 160);
    transpose_k<<<dim3(1, 1024), 256, 0, stream>>>(Wg2, wg2t, 160, 1024);

    // --- G1: t1 = tanh(mix @ A)  (N=160 pad 256, K=1024) ---
    mix_k<<<16384, 256, 0, stream>>>(x, xla, mux, mixb);
    gemm_mfma<ACT_TANH, EPI_NONE, 1><<<dim3(2, 128), 256, 0, stream>>>(
        256, 1024, 160, 160, mixb, at_, nullptr, t1, nullptr);

    // --- f=0: w = tdmu + tanh(w0 @ tdA) @ tdB ---
    xdd_k<<<4096, 256, 0, stream>>>(x, xla, t1, blora, lam, xddb, 0);
    gemm_mfma<ACT_TANH, EPI_NONE, 1><<<dim3(1, 128), 256, 0, stream>>>(
        128, 1024, 64, 64, xddb, tdat, nullptr, tanh64, nullptr);
    gemm_mfma<ACT_NONE, EPI_ADDVEC, 0><<<dim3(8, 128), 256, 0, stream>>>(
        1024, 64, 1024, 1024, tanh64, tdbt, w, nullptr, tdmu);

    // --- f=1: k = (k0 @ Wk^T) * exp(min(w,0)) -> bf16 ---
    xdd_k<<<4096, 256, 0, stream>>>(x, xla, t1, blora, lam, xddb, 1);
    gemm_mfma<ACT_NONE, EPI_KSCALE, 1><<<dim3(8, 128), 256, 0, stream>>>(
        1024, 1024, 1024, 1024, xddb, wkt, nullptr, kbuf, w);

    // --- w -> d = exp(-exp(w)) in place (raw w no longer needed) ---
    decay_k<<<16384, 256, 0, stream>>>(w);

    // --- f=2: v ---
    xdd_k<<<4096, 256, 0, stream>>>(x, xla, t1, blora, lam, xddb, 2);
    gemm_mfma<ACT_NONE, EPI_NONE, 1><<<dim3(8, 128), 256, 0, stream>>>(
        1024, 1024, 1024, 1024, xddb, wvt, nullptr, vbuf, nullptr);

    // --- f=3: r ---
    xdd_k<<<4096, 256, 0, stream>>>(x, xla, t1, blora, lam, xddb, 3);
    gemm_mfma<ACT_NONE, EPI_NONE, 1><<<dim3(8, 128), 256, 0, stream>>>(
        1024, 1024, 1024, 1024, xddb, wrt, nullptr, rbuf, nullptr);

    // --- f=4: g = tanh(g0 @ Wg1) @ Wg2 ---
    xdd_k<<<4096, 256, 0, stream>>>(x, xla, t1, blora, lam, xddb, 4);
    gemm_mfma<ACT_TANH, EPI_NONE, 1><<<dim3(2, 128), 256, 0, stream>>>(
        256, 1024, 160, 160, xddb, wg1t, nullptr, tanhg, nullptr);
    gemm_mfma<ACT_NONE, EPI_NONE, 1><<<dim3(8, 128), 256, 0, stream>>>(
        1024, 160, 1024, 1024, tanhg, wg2t, nullptr, gbuf, nullptr);

    // --- WKV scan: chunked-parallel over T (16 chunks x 128 steps) ---
    zero_k<<<16384, 256, 0, stream>>>((float4*)y0);
    wkv_p1<<<16384, 64, 0, stream>>>(kbuf, vbuf, w, slocal, dprod);
    wkv_p2<<<1024, 64, 0, stream>>>(s_in, slocal, dprod, sstart, snew);
    wkv_p3<<<16384, 64, 0, stream>>>(rbuf, kbuf, vbuf, w, u, sstart, y0);

    // --- GroupNorm(y0)*g -> z (reuses kbuf) ---
    gn_k<<<16384, 256, 0, stream>>>(y0, gbuf, gam, bet, kbuf);

    // --- out = z @ Wo^T (fp32, overwrites w scratch) ---
    gemm_mfma<ACT_NONE, EPI_NONE, 0><<<dim3(8, 128), 256, 0, stream>>>(
        1024, 1024, 1024, 1024, kbuf, wot, out, nullptr, nullptr);

    // --- x_raw = x ---
    copy_k<<<16384, 256, 0, stream>>>((const float4*)x, (float4*)xraw);
}

// Round 6
// 1601.960 us; speedup vs baseline: 1.4353x; 1.0461x over previous
//
#include <hip/hip_runtime.h>
#include <hip/hip_bf16.h>

namespace {

typedef __attribute__((ext_vector_type(8))) short short8x;
typedef __attribute__((ext_vector_type(4))) float f32x4;

__device__ __forceinline__ float bf2f(unsigned short h) {
    return __uint_as_float(((unsigned int)h) << 16);
}
__device__ __forceinline__ unsigned short f2bf(float f) {
    __hip_bfloat16 h = __float2bfloat16(f);
    return *reinterpret_cast<unsigned short*>(&h);
}

enum { ACT_NONE = 0, ACT_TANH = 1 };
enum { EPI_NONE = 0, EPI_KSCALE = 1, EPI_ADDVEC = 2 };

// ---------------- bf16 MFMA GEMM: C[m,n] = sum_k A[m,k]*B[n,k] -----------------
// A: M x K bf16 row-major (M=16384). B: Npad x K bf16 row-major (padded w/ zeros).
// 128x128 tile, 256 threads (4 waves, 2x2 of 64x64), BK=32, one 16x16x32 MFMA
// per 16x16 tile per k-iter. LDS XOR-swizzled (chunk ^= (row>>1)&3) -> 2-way max.
template <int ACT, int EPI, int SBF>
__launch_bounds__(256) __global__
void gemm_mfma(int Npad, int K, int Nreal, int Cstride,
               const unsigned short* __restrict__ A,
               const unsigned short* __restrict__ B,
               float* __restrict__ Cf, unsigned short* __restrict__ Cb,
               const float* __restrict__ epi)
{
    __shared__ unsigned short as_[128 * 32];
    __shared__ unsigned short bs_[128 * 32];
    const int tid = threadIdx.x;
    const int lane = tid & 63;
    const int wave = tid >> 6;
    const int m0 = blockIdx.y << 7;
    const int n0 = blockIdx.x << 7;
    const int wm = (wave >> 1) << 6;
    const int wn = (wave & 1) << 6;

    f32x4 acc[4][4];
    const f32x4 zero = {0.f, 0.f, 0.f, 0.f};
#pragma unroll
    for (int i = 0; i < 4; ++i)
#pragma unroll
        for (int j = 0; j < 4; ++j) acc[i][j] = zero;

    const int sr = tid >> 2;       // row within 64-row chunk
    const int sc4 = tid & 3;       // 8-elt chunk within 32-wide row

    for (int k0 = 0; k0 < K; k0 += 32) {
        const uint4 a0 = *(const uint4*)(A + (size_t)(m0 + sr) * K + k0 + sc4 * 8);
        const uint4 a1 = *(const uint4*)(A + (size_t)(m0 + 64 + sr) * K + k0 + sc4 * 8);
        const uint4 b0 = *(const uint4*)(B + (size_t)(n0 + sr) * K + k0 + sc4 * 8);
        const uint4 b1 = *(const uint4*)(B + (size_t)(n0 + 64 + sr) * K + k0 + sc4 * 8);
        __syncthreads();  // previous iter's LDS reads done
        {
            int r = sr, p = sc4 ^ ((r >> 1) & 3);
            *(uint4*)&as_[r * 32 + p * 8] = a0;
            *(uint4*)&bs_[r * 32 + p * 8] = b0;
            r = 64 + sr; p = sc4 ^ ((r >> 1) & 3);
            *(uint4*)&as_[r * 32 + p * 8] = a1;
            *(uint4*)&bs_[r * 32 + p * 8] = b1;
        }
        __syncthreads();
        const int q = lane >> 4;
        const int l15 = lane & 15;
        short8x af[4], bfr[4];
#pragma unroll
        for (int i = 0; i < 4; ++i) {
            const int m = wm + (i << 4) + l15;
            const int pa = q ^ ((m >> 1) & 3);
            af[i] = *(const short8x*)&as_[m * 32 + pa * 8];
            const int n = wn + (i << 4) + l15;
            const int pb = q ^ ((n >> 1) & 3);
            bfr[i] = *(const short8x*)&bs_[n * 32 + pb * 8];
        }
#pragma unroll
        for (int i = 0; i < 4; ++i)
#pragma unroll
            for (int j = 0; j < 4; ++j)
                acc[i][j] = __builtin_amdgcn_mfma_f32_16x16x32_bf16(af[i], bfr[j], acc[i][j], 0, 0, 0);
    }

    const int q = lane >> 4;
    const int cn = lane & 15;
#pragma unroll
    for (int i = 0; i < 4; ++i) {
#pragma unroll
        for (int j = 0; j < 4; ++j) {
#pragma unroll
            for (int rr = 0; rr < 4; ++rr) {
                const int row = m0 + wm + (i << 4) + (q << 2) + rr;
                const int col = n0 + wn + (j << 4) + cn;
                if (col >= Nreal) continue;
                float v = acc[i][j][rr];
                if constexpr (ACT == ACT_TANH) v = tanhf(v);
                if constexpr (EPI == EPI_KSCALE)
                    v *= __expf(fminf(epi[(size_t)row * 1024 + col], 0.f));
                if constexpr (EPI == EPI_ADDVEC) v += epi[col];
                if constexpr (SBF) Cb[(size_t)row * Cstride + col] = f2bf(v);
                else               Cf[(size_t)row * Cstride + col] = v;
            }
        }
    }
}

// mix[m,c] = bf16(x + (x_last - x) * miu_x[c])
__launch_bounds__(256) __global__
void mix_k(const float* __restrict__ x, const float* __restrict__ xla,
           const float* __restrict__ mux, unsigned short* __restrict__ out)
{
    const size_t idx = ((size_t)blockIdx.x * 256 + threadIdx.x) * 4;
    const int c = (int)(idx & 1023);
    const float4 xv = *(const float4*)(x + idx);
    const float4 xl = *(const float4*)(xla + idx);
    const float4 mu = *(const float4*)(mux + c);
    ushort4 o;
    o.x = f2bf(xv.x + (xl.x - xv.x) * mu.x);
    o.y = f2bf(xv.y + (xl.y - xv.y) * mu.y);
    o.z = f2bf(xv.z + (xl.z - xv.z) * mu.z);
    o.w = f2bf(xv.w + (xl.w - xv.w) * mu.w);
    *(ushort4*)(out + idx) = o;
}

// plain fp32 -> bf16 convert (n mult of 1024; grid = n/1024)
__launch_bounds__(256) __global__
void convert_k(const float* __restrict__ src, unsigned short* __restrict__ dst)
{
    const size_t idx = ((size_t)blockIdx.x * 256 + threadIdx.x) * 4;
    const float4 v = *(const float4*)(src + idx);
    ushort4 o;
    o.x = f2bf(v.x); o.y = f2bf(v.y); o.z = f2bf(v.z); o.w = f2bf(v.w);
    *(ushort4*)(dst + idx) = o;
}

// dst[n*K + k] = (n < Nsrc) ? bf16(src[k*Nsrc + n]) : 0   (grid.y = Npad rows)
__launch_bounds__(256) __global__
void transpose_k(const float* __restrict__ src, unsigned short* __restrict__ dst,
                 int K, int Nsrc)
{
    const int k = blockIdx.x * 256 + threadIdx.x;
    const int n = blockIdx.y;
    if (k < K)
        dst[(size_t)n * K + k] = (n < Nsrc) ? f2bf(src[(size_t)k * Nsrc + n]) : (unsigned short)0;
}

// xdd[f][m,c] = x + (x_last-x) * (lambda[f,c] + sum_kk t1flat[f*524288+m*32+kk]*B_lora[f,kk,c])
__launch_bounds__(256) __global__
void xdd_k(const float* __restrict__ x, const float* __restrict__ xla,
           const unsigned short* __restrict__ t1, const float* __restrict__ blora,
           const float* __restrict__ lam, unsigned short* __restrict__ out, int f)
{
    __shared__ float sh[4][32];
    const int tid = threadIdx.x;
    const int m0 = blockIdx.x << 2;
    if (tid < 128) {
        const int r = tid >> 5, kk = tid & 31;
        sh[r][kk] = bf2f(t1[(size_t)f * 524288 + (size_t)(m0 + r) * 32 + kk]);
    }
    __syncthreads();
    const int c0 = tid << 2;
    const float* bl = blora + f * 32768 + c0;
    float dot[4][4];
#pragma unroll
    for (int r = 0; r < 4; ++r)
#pragma unroll
        for (int j = 0; j < 4; ++j) dot[r][j] = 0.f;
    for (int kk = 0; kk < 32; ++kk) {
        const float4 b4 = *(const float4*)(bl + (size_t)kk * 1024);
#pragma unroll
        for (int r = 0; r < 4; ++r) {
            const float tv = sh[r][kk];
            dot[r][0] = fmaf(tv, b4.x, dot[r][0]);
            dot[r][1] = fmaf(tv, b4.y, dot[r][1]);
            dot[r][2] = fmaf(tv, b4.z, dot[r][2]);
            dot[r][3] = fmaf(tv, b4.w, dot[r][3]);
        }
    }
    const float4 l4 = *(const float4*)(lam + f * 1024 + c0);
#pragma unroll
    for (int r = 0; r < 4; ++r) {
        const size_t idx = (size_t)(m0 + r) * 1024 + c0;
        const float4 xv = *(const float4*)(x + idx);
        const float4 xl = *(const float4*)(xla + idx);
        ushort4 o;
        o.x = f2bf(xv.x + (xl.x - xv.x) * (l4.x + dot[r][0]));
        o.y = f2bf(xv.y + (xl.y - xv.y) * (l4.y + dot[r][1]));
        o.z = f2bf(xv.z + (xl.z - xv.z) * (l4.z + dot[r][2]));
        o.w = f2bf(xv.w + (xl.w - xv.w) * (l4.w + dot[r][3]));
        *(ushort4*)(out + idx) = o;
    }
}

// in-place decay: p = exp(-exp(p))  (16M elems, grid 16384)
__launch_bounds__(256) __global__
void decay_k(float* __restrict__ p)
{
    const size_t idx = ((size_t)blockIdx.x * 256 + threadIdx.x) * 4;
    const float4 v = *(const float4*)(p + idx);
    float4 o;
    o.x = __expf(-__expf(v.x));
    o.y = __expf(-__expf(v.y));
    o.z = __expf(-__expf(v.z));
    o.w = __expf(-__expf(v.w));
    *(float4*)(p + idx) = o;
}

// ---------------- WKV6: chunked-parallel linear scan over T ------------------
// s_t = d_t (*) s_{t-1} + k_t (x) v_t is linear -> split T=2048 into 16 chunks
// of 128. pass1: chunk-local scan (s=0), emits end-state sloc + decay product
// D = prod(d). pass2: tiny sequential combine s_start[c+1] = D[c]*s_start[c]
// + sloc[c]. pass3: per-chunk scan from true start state, emitting y.
// pass3 is ATOMIC-FREE (round-5 post-mortem: 512 MB of fp32 atomics hit HBM
// individually at ~1 TB/s = the 500 us): the 8 j-chunks of one (bh,tc) are 8
// WAVES of one 512-thread block; per 4-step group each wave dumps its 8-row
// partial y to a ping-pong LDS slot, one __syncthreads, waves 0-3 reduce 8
// partials and issue ONE plain coalesced store per (t,i). y write traffic:
// 512 MB atomic -> 64 MB plain; zero-fill pass deleted (full overwrite).
#define BF_LO(x) __uint_as_float((x) << 16)
#define BF_HI(x) __uint_as_float((x) & 0xFFFF0000u)

#define WKV_LOAD(RV, KV, DV, VVv, T0)                                         \
    do {                                                                      \
        _Pragma("unroll")                                                     \
        for (int tt = 0; tt < 4; ++tt) {                                      \
            const size_t o_ = (size_t)((T0) + tt) * 1024;                     \
            RV[tt] = *(const uint4*)(rp + o_);                                \
            KV[tt] = *(const uint4*)(kp + o_);                                \
            DV[tt][0] = *(const float4*)(dp + o_);                            \
            DV[tt][1] = *(const float4*)(dp + o_ + 4);                        \
            VVv[tt] = vp[o_];                                                 \
        }                                                                     \
    } while (0)

// compute 4 steps; partial y -> LDS slot; reduce across 8 waves; plain store
#define P3_PROC(RV, KV, DV, VVv, SLOT, T0)                                    \
    do {                                                                      \
        _Pragma("unroll")                                                     \
        for (int tt = 0; tt < 4; ++tt) {                                      \
            const float vi_ = bf2f(VVv[tt]);                                  \
            float rj[8], kj[8], dj[8];                                        \
            rj[0] = BF_LO(RV[tt].x); rj[1] = BF_HI(RV[tt].x);                 \
            rj[2] = BF_LO(RV[tt].y); rj[3] = BF_HI(RV[tt].y);                 \
            rj[4] = BF_LO(RV[tt].z); rj[5] = BF_HI(RV[tt].z);                 \
            rj[6] = BF_LO(RV[tt].w); rj[7] = BF_HI(RV[tt].w);                 \
            kj[0] = BF_LO(KV[tt].x); kj[1] = BF_HI(KV[tt].x);                 \
            kj[2] = BF_LO(KV[tt].y); kj[3] = BF_HI(KV[tt].y);                 \
            kj[4] = BF_LO(KV[tt].z); kj[5] = BF_HI(KV[tt].z);                 \
            kj[6] = BF_LO(KV[tt].w); kj[7] = BF_HI(KV[tt].w);                 \
            dj[0] = DV[tt][0].x; dj[1] = DV[tt][0].y;                         \
            dj[2] = DV[tt][0].z; dj[3] = DV[tt][0].w;                         \
            dj[4] = DV[tt][1].x; dj[5] = DV[tt][1].y;                         \
            dj[6] = DV[tt][1].z; dj[7] = DV[tt][1].w;                         \
            float ya0_ = 0.f, ya1_ = 0.f;                                     \
            _Pragma("unroll")                                                 \
            for (int jj = 0; jj < 8; ++jj) {                                  \
                const float t_ = kj[jj] * vi_;                                \
                const float a_ = fmaf(u8[jj], t_, s[jj]);                     \
                if (jj & 1) ya1_ = fmaf(rj[jj], a_, ya1_);                    \
                else        ya0_ = fmaf(rj[jj], a_, ya0_);                    \
                s[jj] = fmaf(dj[jj], s[jj], t_);                              \
            }                                                                 \
            red[SLOT][w][tt][l] = ya0_ + ya1_;                                \
        }                                                                     \
        __syncthreads();                                                      \
        if (w < 4) {                                                          \
            float acc_ = red[SLOT][0][w][l];                                  \
            _Pragma("unroll")                                                 \
            for (int w_ = 1; w_ < 8; ++w_) acc_ += red[SLOT][w_][w][l];       \
            yp[(size_t)((T0) + w) * 1024] = acc_;                             \
        }                                                                     \
    } while (0)

#define P1_LOAD(KV, DV, VVv, T0)                                              \
    do {                                                                      \
        _Pragma("unroll")                                                     \
        for (int tt = 0; tt < 4; ++tt) {                                      \
            const size_t o_ = (size_t)((T0) + tt) * 1024;                     \
            KV[tt] = *(const uint4*)(kp + o_);                                \
            DV[tt][0] = *(const float4*)(dp + o_);                            \
            DV[tt][1] = *(const float4*)(dp + o_ + 4);                        \
            VVv[tt] = vp[o_];                                                 \
        }                                                                     \
    } while (0)

#define P1_PROC(KV, DV, VVv)                                                  \
    do {                                                                      \
        _Pragma("unroll")                                                     \
        for (int tt = 0; tt < 4; ++tt) {                                      \
            const float vi_ = bf2f(VVv[tt]);                                  \
            float kj[8], dj[8];                                               \
            kj[0] = BF_LO(KV[tt].x); kj[1] = BF_HI(KV[tt].x);                 \
            kj[2] = BF_LO(KV[tt].y); kj[3] = BF_HI(KV[tt].y);                 \
            kj[4] = BF_LO(KV[tt].z); kj[5] = BF_HI(KV[tt].z);                 \
            kj[6] = BF_LO(KV[tt].w); kj[7] = BF_HI(KV[tt].w);                 \
            dj[0] = DV[tt][0].x; dj[1] = DV[tt][0].y;                         \
            dj[2] = DV[tt][0].z; dj[3] = DV[tt][0].w;                         \
            dj[4] = DV[tt][1].x; dj[5] = DV[tt][1].y;                         \
            dj[6] = DV[tt][1].z; dj[7] = DV[tt][1].w;                         \
            _Pragma("unroll")                                                 \
            for (int jj = 0; jj < 8; ++jj) {                                  \
                const float t_ = kj[jj] * vi_;                                \
                s[jj] = fmaf(dj[jj], s[jj], t_);                              \
                D[jj] *= dj[jj];                                              \
            }                                                                 \
        }                                                                     \
    } while (0)

// pass1: per (bh, t-chunk, j-chunk): local scan (s=0), write sloc + D.
__launch_bounds__(64) __global__
void wkv_p1(const unsigned short* __restrict__ k, const unsigned short* __restrict__ v,
            const float* __restrict__ d,
            float* __restrict__ slocal, float* __restrict__ dprod)
{
    const int blk = blockIdx.x;
    const int bh = blk & 127;
    const int jc = (blk >> 7) & 7;
    const int tc = blk >> 10;
    const int h = bh & 15;
    const int l = threadIdx.x;
    const int jbase = jc << 3;

    float s[8], D[8];
#pragma unroll
    for (int jj = 0; jj < 8; ++jj) { s[jj] = 0.f; D[jj] = 1.f; }

    const size_t base = (size_t)(bh >> 4) * (2048 * 1024) + (size_t)tc * 131072 + (h << 6);
    const unsigned short* kp = k + base + jbase;
    const float*          dp = d + base + jbase;
    const unsigned short* vp = v + base + l;

    uint4 kA[4]; float4 dA[4][2]; unsigned short vA[4];
    uint4 kB[4]; float4 dB[4][2]; unsigned short vB[4];

    P1_LOAD(kA, dA, vA, 0);
    for (int c = 0; c < 32; c += 2) {
        P1_LOAD(kB, dB, vB, (c + 1) * 4);
        P1_PROC(kA, dA, vA);
        if (c + 2 < 32) P1_LOAD(kA, dA, vA, (c + 2) * 4);
        P1_PROC(kB, dB, vB);
    }
    const size_t cb = (size_t)(tc * 128 + bh) * 64 + jbase;
#pragma unroll
    for (int jj = 0; jj < 8; ++jj) slocal[(cb + jj) * 64 + l] = s[jj];
    if (l == 0) {
#pragma unroll
        for (int jj = 0; jj < 8; ++jj) dprod[cb + jj] = D[jj];
    }
}

// pass2: per (bh, j-chunk): sequential combine over 16 chunks.
// sstart[c] = state at chunk start; s_out = state after chunk 15.
__launch_bounds__(64) __global__
void wkv_p2(const float* __restrict__ s_in, const float* __restrict__ slocal,
            const float* __restrict__ dprod, float* __restrict__ sstart,
            float* __restrict__ s_out)
{
    const int blk = blockIdx.x;
    const int bh = blk & 127;
    const int jc = blk >> 7;
    const int l = threadIdx.x;
    const int jbase = jc << 3;

    float s[8];
    const size_t sb = (size_t)bh * 4096;
#pragma unroll
    for (int jj = 0; jj < 8; ++jj) s[jj] = s_in[sb + (size_t)(jbase + jj) * 64 + l];

    for (int c = 0; c < 16; ++c) {
        const size_t cb = (size_t)(c * 128 + bh) * 64 + jbase;
#pragma unroll
        for (int jj = 0; jj < 8; ++jj) sstart[(cb + jj) * 64 + l] = s[jj];
#pragma unroll
        for (int jj = 0; jj < 8; ++jj)
            s[jj] = fmaf(dprod[cb + jj], s[jj], slocal[(cb + jj) * 64 + l]);
    }
#pragma unroll
    for (int jj = 0; jj < 8; ++jj) s_out[sb + (size_t)(jbase + jj) * 64 + l] = s[jj];
}

// pass3: block = (bh, t-chunk), 8 waves = 8 j-chunks; LDS cross-wave reduce;
// plain coalesced y stores (no atomics).
__launch_bounds__(512) __global__
void wkv_p3(const unsigned short* __restrict__ r, const unsigned short* __restrict__ k,
            const unsigned short* __restrict__ v, const float* __restrict__ d,
            const float* __restrict__ u, const float* __restrict__ sstart,
            float* __restrict__ y)
{
    const int blk = blockIdx.x;
    const int bh = blk & 127;
    const int tc = blk >> 7;
    const int h = bh & 15;
    const int tid = threadIdx.x;
    const int w = tid >> 6;        // wave = j-chunk
    const int l = tid & 63;        // value column i
    const int jbase = w << 3;

    __shared__ float red[2][8][4][64];   // [slot][wave][tt][i] = 16 KB

    float s[8];
    const size_t cb = (size_t)(tc * 128 + bh) * 64 + jbase;
#pragma unroll
    for (int jj = 0; jj < 8; ++jj) s[jj] = sstart[(cb + jj) * 64 + l];

    float u8[8];
#pragma unroll
    for (int jj = 0; jj < 8; ++jj) u8[jj] = u[(h << 6) + jbase + jj];

    const size_t base = (size_t)(bh >> 4) * (2048 * 1024) + (size_t)tc * 131072 + (h << 6);
    const unsigned short* rp = r + base + jbase;
    const unsigned short* kp = k + base + jbase;
    const float*          dp = d + base + jbase;
    const unsigned short* vp = v + base + l;
    float*                yp = y + base + l;

    uint4 rA[4], kA[4]; float4 dA[4][2]; unsigned short vA[4];
    uint4 rB[4], kB[4]; float4 dB[4][2]; unsigned short vB[4];

    WKV_LOAD(rA, kA, dA, vA, 0);
    for (int c = 0; c < 32; c += 2) {
        WKV_LOAD(rB, kB, dB, vB, (c + 1) * 4);
        P3_PROC(rA, kA, dA, vA, 0, c * 4);
        if (c + 2 < 32) WKV_LOAD(rA, kA, dA, vA, (c + 2) * 4);
        P3_PROC(rB, kB, dB, vB, 1, (c + 1) * 4);
    }
}

// GroupNorm over heads of 64 ch (eps = 1e-5*16), then *g, store bf16 z.
__launch_bounds__(256) __global__
void gn_k(const float* __restrict__ y0,
          const unsigned short* __restrict__ g, const float* __restrict__ gam,
          const float* __restrict__ bet, unsigned short* __restrict__ z)
{
    const int tid = threadIdx.x;
    const size_t row = blockIdx.x;
    const int c0 = tid << 2;
    const size_t idx = row * 1024 + c0;
    const float4 a = *(const float4*)(y0 + idx);
    const float yv0 = a.x, yv1 = a.y, yv2 = a.z, yv3 = a.w;
    float sm = yv0 + yv1 + yv2 + yv3;
    float q = yv0 * yv0 + yv1 * yv1 + yv2 * yv2 + yv3 * yv3;
#pragma unroll
    for (int off = 1; off < 16; off <<= 1) {
        sm += __shfl_xor(sm, off, 64);
        q += __shfl_xor(q, off, 64);
    }
    const float mean = sm * (1.f / 64.f);
    const float var = q * (1.f / 64.f) - mean * mean;
    const float rstd = rsqrtf(var + 1.6e-4f);
    const float4 gm = *(const float4*)(gam + c0);
    const float4 bt = *(const float4*)(bet + c0);
    const ushort4 gg = *(const ushort4*)(g + idx);
    ushort4 o;
    o.x = f2bf(((yv0 - mean) * rstd * gm.x + bt.x) * bf2f(gg.x));
    o.y = f2bf(((yv1 - mean) * rstd * gm.y + bt.y) * bf2f(gg.y));
    o.z = f2bf(((yv2 - mean) * rstd * gm.z + bt.z) * bf2f(gg.z));
    o.w = f2bf(((yv3 - mean) * rstd * gm.w + bt.w) * bf2f(gg.w));
    *(ushort4*)(z + idx) = o;
}

__launch_bounds__(256) __global__
void copy_k(const float4* __restrict__ src, float4* __restrict__ dst)
{
    const size_t i = (size_t)blockIdx.x * 256 + threadIdx.x;
    dst[i] = src[i];
}

}  // namespace

extern "C" void kernel_launch(void* const* d_in, const int* in_sizes, int n_in,
                              void* d_out, int out_size, void* d_ws, size_t ws_size,
                              hipStream_t stream)
{
    (void)in_sizes; (void)n_in; (void)out_size; (void)ws_size;
    const float* x     = (const float*)d_in[0];
    const float* xla   = (const float*)d_in[1];
    const float* s_in  = (const float*)d_in[2];
    const float* mux   = (const float*)d_in[3];
    const float* lam   = (const float*)d_in[4];
    const float* Amat  = (const float*)d_in[5];
    const float* blora = (const float*)d_in[6];
    const float* tdmu  = (const float*)d_in[7];
    const float* tdA   = (const float*)d_in[8];
    const float* tdB   = (const float*)d_in[9];
    const float* u     = (const float*)d_in[10];
    const float* Wk    = (const float*)d_in[11];
    const float* Wv    = (const float*)d_in[12];
    const float* Wr    = (const float*)d_in[13];
    const float* Wo    = (const float*)d_in[14];
    const float* Wg1   = (const float*)d_in[15];
    const float* Wg2   = (const float*)d_in[16];
    const float* gam   = (const float*)d_in[17];
    const float* bet   = (const float*)d_in[18];

    float* out  = (float*)d_out;          // w-scratch until final GEMM
    float* xraw = out + 16777216;         // y0 scratch until final copy
    float* snew = out + 2 * 16777216;

    char* ws = (char*)d_ws;
    unsigned short* mixb   = (unsigned short*)(ws);              // 32 MB (dead after G1 -> slocal)
    unsigned short* xddb   = (unsigned short*)(ws + 33554432);   // 32 MB (dead after f=4 gemm -> sstart)
    unsigned short* t1     = (unsigned short*)(ws + 67108864);   // 5.25 MB (dead after f=4 xdd -> dprod)
    unsigned short* tanh64 = (unsigned short*)(ws + 72351744);   // 2 MB
    unsigned short* tanhg  = (unsigned short*)(ws + 74448896);   // 5.25 MB
    unsigned short* kbuf   = (unsigned short*)(ws + 79691776);   // 32 MB (-> z after wkv)
    unsigned short* vbuf   = (unsigned short*)(ws + 113246208);  // 32 MB
    unsigned short* rbuf   = (unsigned short*)(ws + 146800640);  // 32 MB
    unsigned short* gbuf   = (unsigned short*)(ws + 180355072);  // 32 MB
    unsigned short* wkt    = (unsigned short*)(ws + 213909504);  // 2 MB
    unsigned short* wvt    = (unsigned short*)(ws + 216006656);
    unsigned short* wrt    = (unsigned short*)(ws + 218103808);
    unsigned short* wot    = (unsigned short*)(ws + 220200960);
    unsigned short* at_    = (unsigned short*)(ws + 222298112);  // 256x1024
    unsigned short* tdat   = (unsigned short*)(ws + 222822400);  // 128x1024
    unsigned short* tdbt   = (unsigned short*)(ws + 223084544);  // 1024x64
    unsigned short* wg1t   = (unsigned short*)(ws + 223215616);  // 256x1024
    unsigned short* wg2t   = (unsigned short*)(ws + 223739904);  // 1024x160 (end ~224 MB)

    float* w  = out;            // 16384x1024 fp32 (becomes decay d in-place)
    float* y0 = xraw;           // fp32 y buffer (plain stores, full overwrite)
    float* slocal = (float*)ws;               // 32 MB (over dead mixb)
    float* sstart = (float*)(ws + 33554432);  // 32 MB (over dead xddb)
    float* dprod  = (float*)(ws + 67108864);  // 512 KB (over dead t1)

    // --- weight conversions ---
    convert_k<<<1024, 256, 0, stream>>>(Wk, wkt);
    convert_k<<<1024, 256, 0, stream>>>(Wv, wvt);
    convert_k<<<1024, 256, 0, stream>>>(Wr, wrt);
    convert_k<<<1024, 256, 0, stream>>>(Wo, wot);
    transpose_k<<<dim3(4, 256), 256, 0, stream>>>(Amat, at_, 1024, 160);
    transpose_k<<<dim3(4, 128), 256, 0, stream>>>(tdA, tdat, 1024, 64);
    transpose_k<<<dim3(1, 1024), 256, 0, stream>>>(tdB, tdbt, 64, 1024);
    transpose_k<<<dim3(4, 256), 256, 0, stream>>>(Wg1, wg1t, 1024, 160);
    transpose_k<<<dim3(1, 1024), 256, 0, stream>>>(Wg2, wg2t, 160, 1024);

    // --- G1: t1 = tanh(mix @ A)  (N=160 pad 256, K=1024) ---
    mix_k<<<16384, 256, 0, stream>>>(x, xla, mux, mixb);
    gemm_mfma<ACT_TANH, EPI_NONE, 1><<<dim3(2, 128), 256, 0, stream>>>(
        256, 1024, 160, 160, mixb, at_, nullptr, t1, nullptr);

    // --- f=0: w = tdmu + tanh(w0 @ tdA) @ tdB ---
    xdd_k<<<4096, 256, 0, stream>>>(x, xla, t1, blora, lam, xddb, 0);
    gemm_mfma<ACT_TANH, EPI_NONE, 1><<<dim3(1, 128), 256, 0, stream>>>(
        128, 1024, 64, 64, xddb, tdat, nullptr, tanh64, nullptr);
    gemm_mfma<ACT_NONE, EPI_ADDVEC, 0><<<dim3(8, 128), 256, 0, stream>>>(
        1024, 64, 1024, 1024, tanh64, tdbt, w, nullptr, tdmu);

    // --- f=1: k = (k0 @ Wk^T) * exp(min(w,0)) -> bf16 ---
    xdd_k<<<4096, 256, 0, stream>>>(x, xla, t1, blora, lam, xddb, 1);
    gemm_mfma<ACT_NONE, EPI_KSCALE, 1><<<dim3(8, 128), 256, 0, stream>>>(
        1024, 1024, 1024, 1024, xddb, wkt, nullptr, kbuf, w);

    // --- w -> d = exp(-exp(w)) in place (raw w no longer needed) ---
    decay_k<<<16384, 256, 0, stream>>>(w);

    // --- f=2: v ---
    xdd_k<<<4096, 256, 0, stream>>>(x, xla, t1, blora, lam, xddb, 2);
    gemm_mfma<ACT_NONE, EPI_NONE, 1><<<dim3(8, 128), 256, 0, stream>>>(
        1024, 1024, 1024, 1024, xddb, wvt, nullptr, vbuf, nullptr);

    // --- f=3: r ---
    xdd_k<<<4096, 256, 0, stream>>>(x, xla, t1, blora, lam, xddb, 3);
    gemm_mfma<ACT_NONE, EPI_NONE, 1><<<dim3(8, 128), 256, 0, stream>>>(
        1024, 1024, 1024, 1024, xddb, wrt, nullptr, rbuf, nullptr);

    // --- f=4: g = tanh(g0 @ Wg1) @ Wg2 ---
    xdd_k<<<4096, 256, 0, stream>>>(x, xla, t1, blora, lam, xddb, 4);
    gemm_mfma<ACT_TANH, EPI_NONE, 1><<<dim3(2, 128), 256, 0, stream>>>(
        256, 1024, 160, 160, xddb, wg1t, nullptr, tanhg, nullptr);
    gemm_mfma<ACT_NONE, EPI_NONE, 1><<<dim3(8, 128), 256, 0, stream>>>(
        1024, 160, 1024, 1024, tanhg, wg2t, nullptr, gbuf, nullptr);

    // --- WKV scan: chunked-parallel over T (16 chunks x 128 steps) ---
    wkv_p1<<<16384, 64, 0, stream>>>(kbuf, vbuf, w, slocal, dprod);
    wkv_p2<<<1024, 64, 0, stream>>>(s_in, slocal, dprod, sstart, snew);
    wkv_p3<<<2048, 512, 0, stream>>>(rbuf, kbuf, vbuf, w, u, sstart, y0);

    // --- GroupNorm(y0)*g -> z (reuses kbuf) ---
    gn_k<<<16384, 256, 0, stream>>>(y0, gbuf, gam, bet, kbuf);

    // --- out = z @ Wo^T (fp32, overwrites w scratch) ---
    gemm_mfma<ACT_NONE, EPI_NONE, 0><<<dim3(8, 128), 256, 0, stream>>>(
        1024, 1024, 1024, 1024, kbuf, wot, out, nullptr, nullptr);

    // --- x_raw = x ---
    copy_k<<<16384, 256, 0, stream>>>((const float4*)x, (float4*)xraw);
}

// Round 7
// 1570.157 us; speedup vs baseline: 1.4643x; 1.0203x over previous
//
#include <hip/hip_runtime.h>
#include <hip/hip_bf16.h>

namespace {

typedef __attribute__((ext_vector_type(8))) short short8x;
typedef __attribute__((ext_vector_type(4))) float f32x4;

__device__ __forceinline__ float bf2f(unsigned short h) {
    return __uint_as_float(((unsigned int)h) << 16);
}
__device__ __forceinline__ unsigned short f2bf(float f) {
    __hip_bfloat16 h = __float2bfloat16(f);
    return *reinterpret_cast<unsigned short*>(&h);
}
// async global->LDS, 16B per lane; LDS dest = wave-uniform base + lane*16
__device__ __forceinline__ void gload16(const unsigned short* g, unsigned short* l) {
    __builtin_amdgcn_global_load_lds(
        (const __attribute__((address_space(1))) void*)g,
        (__attribute__((address_space(3))) void*)l, 16, 0, 0);
}

enum { ACT_NONE = 0, ACT_TANH = 1 };
enum { EPI_NONE = 0, EPI_KSCALE = 1, EPI_ADDVEC = 2 };

// ---------------- bf16 MFMA GEMM: C[m,n] = sum_k A[m,k]*B[n,k] -----------------
// A: M x K bf16 row-major. B: Npad x K bf16 row-major (zero-padded).
// 128x128 tile, 256 threads (4 waves, 2x2 of 64x64), BK=32.
// Staging via global_load_lds (m97 pattern): linear LDS, each wave issues 4
// insts (2 A + 2 B) of 1KB; no register round-trip, no LDS writes.
template <int ACT, int EPI, int SBF>
__launch_bounds__(256) __global__
void gemm_mfma(int Npad, int K, int Nreal, int Cstride,
               const unsigned short* __restrict__ A,
               const unsigned short* __restrict__ B,
               float* __restrict__ Cf, unsigned short* __restrict__ Cb,
               const float* __restrict__ epi)
{
    __shared__ unsigned short as_[128 * 32];
    __shared__ unsigned short bs_[128 * 32];
    const int tid = threadIdx.x;
    const int lane = tid & 63;
    const int wave = tid >> 6;
    const int m0 = blockIdx.y << 7;
    const int n0 = blockIdx.x << 7;
    const int wm = (wave >> 1) << 6;
    const int wn = (wave & 1) << 6;

    f32x4 acc[4][4];
    const f32x4 zero = {0.f, 0.f, 0.f, 0.f};
#pragma unroll
    for (int i = 0; i < 4; ++i)
#pragma unroll
        for (int j = 0; j < 4; ++j) acc[i][j] = zero;

    // staging geometry: inst p of wave w covers rows w*32 + p*16 + (lane>>2),
    // col chunk (lane&3)*8; LDS linear elem = (w*2+p)*512 + lane*8.
    const int grow = lane >> 2;
    const int gcol = (lane & 3) << 3;
    const unsigned short* a0p = A + (size_t)(m0 + (wave << 5) + grow) * K + gcol;
    const unsigned short* a1p = A + (size_t)(m0 + (wave << 5) + 16 + grow) * K + gcol;
    const unsigned short* b0p = B + (size_t)(n0 + (wave << 5) + grow) * K + gcol;
    const unsigned short* b1p = B + (size_t)(n0 + (wave << 5) + 16 + grow) * K + gcol;
    unsigned short* la0 = as_ + (wave * 2 + 0) * 512;
    unsigned short* la1 = as_ + (wave * 2 + 1) * 512;
    unsigned short* lb0 = bs_ + (wave * 2 + 0) * 512;
    unsigned short* lb1 = bs_ + (wave * 2 + 1) * 512;

    for (int k0 = 0; k0 < K; k0 += 32) {
        __syncthreads();  // previous iter's LDS reads done
        gload16(a0p + k0, la0);
        gload16(b0p + k0, lb0);
        gload16(a1p + k0, la1);
        gload16(b1p + k0, lb1);
        __syncthreads();  // vmcnt drained by compiler before barrier
        const int q = lane >> 4;
        const int l15 = lane & 15;
        short8x af[4], bfr[4];
#pragma unroll
        for (int i = 0; i < 4; ++i) {
            af[i]  = *(const short8x*)&as_[(wm + (i << 4) + l15) * 32 + q * 8];
            bfr[i] = *(const short8x*)&bs_[(wn + (i << 4) + l15) * 32 + q * 8];
        }
#pragma unroll
        for (int i = 0; i < 4; ++i)
#pragma unroll
            for (int j = 0; j < 4; ++j)
                acc[i][j] = __builtin_amdgcn_mfma_f32_16x16x32_bf16(af[i], bfr[j], acc[i][j], 0, 0, 0);
    }

    const int q = lane >> 4;
    const int cn = lane & 15;
#pragma unroll
    for (int i = 0; i < 4; ++i) {
#pragma unroll
        for (int j = 0; j < 4; ++j) {
#pragma unroll
            for (int rr = 0; rr < 4; ++rr) {
                const int row = m0 + wm + (i << 4) + (q << 2) + rr;
                const int col = n0 + wn + (j << 4) + cn;
                if (col >= Nreal) continue;
                float v = acc[i][j][rr];
                if constexpr (ACT == ACT_TANH) v = tanhf(v);
                if constexpr (EPI == EPI_KSCALE)
                    v *= __expf(fminf(epi[(size_t)row * 1024 + col], 0.f));
                if constexpr (EPI == EPI_ADDVEC) v += epi[col];
                if constexpr (SBF) Cb[(size_t)row * Cstride + col] = f2bf(v);
                else               Cf[(size_t)row * Cstride + col] = v;
            }
        }
    }
}

// mix[m,c] = bf16(x + (x_last - x) * miu_x[c])
__launch_bounds__(256) __global__
void mix_k(const float* __restrict__ x, const float* __restrict__ xla,
           const float* __restrict__ mux, unsigned short* __restrict__ out)
{
    const size_t idx = ((size_t)blockIdx.x * 256 + threadIdx.x) * 4;
    const int c = (int)(idx & 1023);
    const float4 xv = *(const float4*)(x + idx);
    const float4 xl = *(const float4*)(xla + idx);
    const float4 mu = *(const float4*)(mux + c);
    ushort4 o;
    o.x = f2bf(xv.x + (xl.x - xv.x) * mu.x);
    o.y = f2bf(xv.y + (xl.y - xv.y) * mu.y);
    o.z = f2bf(xv.z + (xl.z - xv.z) * mu.z);
    o.w = f2bf(xv.w + (xl.w - xv.w) * mu.w);
    *(ushort4*)(out + idx) = o;
}

// plain fp32 -> bf16 convert (n mult of 1024; grid = n/1024)
__launch_bounds__(256) __global__
void convert_k(const float* __restrict__ src, unsigned short* __restrict__ dst)
{
    const size_t idx = ((size_t)blockIdx.x * 256 + threadIdx.x) * 4;
    const float4 v = *(const float4*)(src + idx);
    ushort4 o;
    o.x = f2bf(v.x); o.y = f2bf(v.y); o.z = f2bf(v.z); o.w = f2bf(v.w);
    *(ushort4*)(dst + idx) = o;
}

// dst[n*K + k] = (n < Nsrc) ? bf16(src[k*Nsrc + n]) : 0   (grid.y = Npad rows)
__launch_bounds__(256) __global__
void transpose_k(const float* __restrict__ src, unsigned short* __restrict__ dst,
                 int K, int Nsrc)
{
    const int k = blockIdx.x * 256 + threadIdx.x;
    const int n = blockIdx.y;
    if (k < K)
        dst[(size_t)n * K + k] = (n < Nsrc) ? f2bf(src[(size_t)k * Nsrc + n]) : (unsigned short)0;
}

// xdd[f][m,c] = x + (x_last-x) * (lambda[f,c] + sum_kk t1flat[f*524288+m*32+kk]*B_lora[f,kk,c])
__launch_bounds__(256) __global__
void xdd_k(const float* __restrict__ x, const float* __restrict__ xla,
           const unsigned short* __restrict__ t1, const float* __restrict__ blora,
           const float* __restrict__ lam, unsigned short* __restrict__ out, int f)
{
    __shared__ float sh[4][32];
    const int tid = threadIdx.x;
    const int m0 = blockIdx.x << 2;
    if (tid < 128) {
        const int r = tid >> 5, kk = tid & 31;
        sh[r][kk] = bf2f(t1[(size_t)f * 524288 + (size_t)(m0 + r) * 32 + kk]);
    }
    __syncthreads();
    const int c0 = tid << 2;
    const float* bl = blora + f * 32768 + c0;
    float dot[4][4];
#pragma unroll
    for (int r = 0; r < 4; ++r)
#pragma unroll
        for (int j = 0; j < 4; ++j) dot[r][j] = 0.f;
    for (int kk = 0; kk < 32; ++kk) {
        const float4 b4 = *(const float4*)(bl + (size_t)kk * 1024);
#pragma unroll
        for (int r = 0; r < 4; ++r) {
            const float tv = sh[r][kk];
            dot[r][0] = fmaf(tv, b4.x, dot[r][0]);
            dot[r][1] = fmaf(tv, b4.y, dot[r][1]);
            dot[r][2] = fmaf(tv, b4.z, dot[r][2]);
            dot[r][3] = fmaf(tv, b4.w, dot[r][3]);
        }
    }
    const float4 l4 = *(const float4*)(lam + f * 1024 + c0);
#pragma unroll
    for (int r = 0; r < 4; ++r) {
        const size_t idx = (size_t)(m0 + r) * 1024 + c0;
        const float4 xv = *(const float4*)(x + idx);
        const float4 xl = *(const float4*)(xla + idx);
        ushort4 o;
        o.x = f2bf(xv.x + (xl.x - xv.x) * (l4.x + dot[r][0]));
        o.y = f2bf(xv.y + (xl.y - xv.y) * (l4.y + dot[r][1]));
        o.z = f2bf(xv.z + (xl.z - xv.z) * (l4.z + dot[r][2]));
        o.w = f2bf(xv.w + (xl.w - xv.w) * (l4.w + dot[r][3]));
        *(ushort4*)(out + idx) = o;
    }
}

// in-place decay: p = exp(-exp(p))  (16M elems, grid 16384)
__launch_bounds__(256) __global__
void decay_k(float* __restrict__ p)
{
    const size_t idx = ((size_t)blockIdx.x * 256 + threadIdx.x) * 4;
    const float4 v = *(const float4*)(p + idx);
    float4 o;
    o.x = __expf(-__expf(v.x));
    o.y = __expf(-__expf(v.y));
    o.z = __expf(-__expf(v.z));
    o.w = __expf(-__expf(v.w));
    *(float4*)(p + idx) = o;
}

// ---------------- WKV6: chunked-parallel linear scan over T ------------------
// 16 chunks of 128 steps. p1: chunk-local scan (s=0) -> sloc. dprod_k: per-
// (tc,bh,j) decay product (was redundant per-lane work inside p1). p2: tiny
// sequential combine. p3: true scan emitting y; 8 waves = 8 j-chunks of one
// (bh,tc); partials cross-wave-reduced in LDS every 8 STEPS (ping-pong slots,
// 16 barriers/block vs 64 in round 6; all 8 waves participate in the reduce).
#define BF_LO(x) __uint_as_float((x) << 16)
#define BF_HI(x) __uint_as_float((x) & 0xFFFF0000u)

#define WKV_LOAD(RV, KV, DV, VVv, T0)                                         \
    do {                                                                      \
        _Pragma("unroll")                                                     \
        for (int tt = 0; tt < 4; ++tt) {                                      \
            const size_t o_ = (size_t)((T0) + tt) * 1024;                     \
            RV[tt] = *(const uint4*)(rp + o_);                                \
            KV[tt] = *(const uint4*)(kp + o_);                                \
            DV[tt][0] = *(const float4*)(dp + o_);                            \
            DV[tt][1] = *(const float4*)(dp + o_ + 4);                        \
            VVv[tt] = vp[o_];                                                 \
        }                                                                     \
    } while (0)

// compute 4 steps; write partial y rows into red[SLOT][w][TH*4+tt][l]
#define P3_COMP(RV, KV, DV, VVv, SLOT, TH)                                    \
    do {                                                                      \
        _Pragma("unroll")                                                     \
        for (int tt = 0; tt < 4; ++tt) {                                      \
            const float vi_ = bf2f(VVv[tt]);                                  \
            float rj[8], kj[8], dj[8];                                        \
            rj[0] = BF_LO(RV[tt].x); rj[1] = BF_HI(RV[tt].x);                 \
            rj[2] = BF_LO(RV[tt].y); rj[3] = BF_HI(RV[tt].y);                 \
            rj[4] = BF_LO(RV[tt].z); rj[5] = BF_HI(RV[tt].z);                 \
            rj[6] = BF_LO(RV[tt].w); rj[7] = BF_HI(RV[tt].w);                 \
            kj[0] = BF_LO(KV[tt].x); kj[1] = BF_HI(KV[tt].x);                 \
            kj[2] = BF_LO(KV[tt].y); kj[3] = BF_HI(KV[tt].y);                 \
            kj[4] = BF_LO(KV[tt].z); kj[5] = BF_HI(KV[tt].z);                 \
            kj[6] = BF_LO(KV[tt].w); kj[7] = BF_HI(KV[tt].w);                 \
            dj[0] = DV[tt][0].x; dj[1] = DV[tt][0].y;                         \
            dj[2] = DV[tt][0].z; dj[3] = DV[tt][0].w;                         \
            dj[4] = DV[tt][1].x; dj[5] = DV[tt][1].y;                         \
            dj[6] = DV[tt][1].z; dj[7] = DV[tt][1].w;                         \
            float ya0_ = 0.f, ya1_ = 0.f;                                     \
            _Pragma("unroll")                                                 \
            for (int jj = 0; jj < 8; ++jj) {                                  \
                const float t_ = kj[jj] * vi_;                                \
                const float a_ = fmaf(u8[jj], t_, s[jj]);                     \
                if (jj & 1) ya1_ = fmaf(rj[jj], a_, ya1_);                    \
                else        ya0_ = fmaf(rj[jj], a_, ya0_);                    \
                s[jj] = fmaf(dj[jj], s[jj], t_);                              \
            }                                                                 \
            red[SLOT][w][(TH) * 4 + tt][l] = ya0_ + ya1_;                     \
        }                                                                     \
    } while (0)

#define P1_LOAD(KV, DV, VVv, T0)                                              \
    do {                                                                      \
        _Pragma("unroll")                                                     \
        for (int tt = 0; tt < 4; ++tt) {                                      \
            const size_t o_ = (size_t)((T0) + tt) * 1024;                     \
            KV[tt] = *(const uint4*)(kp + o_);                                \
            DV[tt][0] = *(const float4*)(dp + o_);                            \
            DV[tt][1] = *(const float4*)(dp + o_ + 4);                       \
            VVv[tt] = vp[o_];                                                 \
        }                                                                     \
    } while (0)

#define P1_PROC(KV, DV, VVv)                                                  \
    do {                                                                      \
        _Pragma("unroll")                                                     \
        for (int tt = 0; tt < 4; ++tt) {                                      \
            const float vi_ = bf2f(VVv[tt]);                                  \
            float kj[8], dj[8];                                               \
            kj[0] = BF_LO(KV[tt].x); kj[1] = BF_HI(KV[tt].x);                 \
            kj[2] = BF_LO(KV[tt].y); kj[3] = BF_HI(KV[tt].y);                 \
            kj[4] = BF_LO(KV[tt].z); kj[5] = BF_HI(KV[tt].z);                 \
            kj[6] = BF_LO(KV[tt].w); kj[7] = BF_HI(KV[tt].w);                 \
            dj[0] = DV[tt][0].x; dj[1] = DV[tt][0].y;                         \
            dj[2] = DV[tt][0].z; dj[3] = DV[tt][0].w;                         \
            dj[4] = DV[tt][1].x; dj[5] = DV[tt][1].y;                         \
            dj[6] = DV[tt][1].z; dj[7] = DV[tt][1].w;                         \
            _Pragma("unroll")                                                 \
            for (int jj = 0; jj < 8; ++jj) {                                  \
                const float t_ = kj[jj] * vi_;                                \
                s[jj] = fmaf(dj[jj], s[jj], t_);                              \
            }                                                                 \
        }                                                                     \
    } while (0)

// pass1: per (bh, t-chunk, j-chunk): local scan (s=0), write sloc.
__launch_bounds__(64) __global__
void wkv_p1(const unsigned short* __restrict__ k, const unsigned short* __restrict__ v,
            const float* __restrict__ d, float* __restrict__ slocal)
{
    const int blk = blockIdx.x;
    const int bh = blk & 127;
    const int jc = (blk >> 7) & 7;
    const int tc = blk >> 10;
    const int h = bh & 15;
    const int l = threadIdx.x;
    const int jbase = jc << 3;

    float s[8];
#pragma unroll
    for (int jj = 0; jj < 8; ++jj) s[jj] = 0.f;

    const size_t base = (size_t)(bh >> 4) * (2048 * 1024) + (size_t)tc * 131072 + (h << 6);
    const unsigned short* kp = k + base + jbase;
    const float*          dp = d + base + jbase;
    const unsigned short* vp = v + base + l;

    uint4 kA[4]; float4 dA[4][2]; unsigned short vA[4];
    uint4 kB[4]; float4 dB[4][2]; unsigned short vB[4];

    P1_LOAD(kA, dA, vA, 0);
    for (int c = 0; c < 32; c += 2) {
        P1_LOAD(kB, dB, vB, (c + 1) * 4);
        P1_PROC(kA, dA, vA);
        if (c + 2 < 32) P1_LOAD(kA, dA, vA, (c + 2) * 4);
        P1_PROC(kB, dB, vB);
    }
    const size_t cb = (size_t)(tc * 128 + bh) * 64 + jbase;
#pragma unroll
    for (int jj = 0; jj < 8; ++jj) slocal[(cb + jj) * 64 + l] = s[jj];
}

// dprod[(tc*128+bh)*64 + j] = prod over the chunk's 128 steps of d[t,j]
__launch_bounds__(64) __global__
void dprod_k(const float* __restrict__ d, float* __restrict__ dprod)
{
    const int blk = blockIdx.x;            // tc*128 + bh
    const int bh = blk & 127;
    const int tc = blk >> 7;
    const int h = bh & 15;
    const int l = threadIdx.x;             // j
    const size_t base = (size_t)(bh >> 4) * (2048 * 1024) + (size_t)tc * 131072 + (h << 6) + l;
    float d0 = 1.f, d1 = 1.f, d2 = 1.f, d3 = 1.f;
    for (int t = 0; t < 128; t += 4) {
        d0 *= d[base + (size_t)t * 1024];
        d1 *= d[base + (size_t)(t + 1) * 1024];
        d2 *= d[base + (size_t)(t + 2) * 1024];
        d3 *= d[base + (size_t)(t + 3) * 1024];
    }
    dprod[(size_t)blk * 64 + l] = (d0 * d1) * (d2 * d3);
}

// pass2: per (bh, j-chunk): sequential combine over 16 chunks.
__launch_bounds__(64) __global__
void wkv_p2(const float* __restrict__ s_in, const float* __restrict__ slocal,
            const float* __restrict__ dprod, float* __restrict__ sstart,
            float* __restrict__ s_out)
{
    const int blk = blockIdx.x;
    const int bh = blk & 127;
    const int jc = blk >> 7;
    const int l = threadIdx.x;
    const int jbase = jc << 3;

    float s[8];
    const size_t sb = (size_t)bh * 4096;
#pragma unroll
    for (int jj = 0; jj < 8; ++jj) s[jj] = s_in[sb + (size_t)(jbase + jj) * 64 + l];

    for (int c = 0; c < 16; ++c) {
        const size_t cb = (size_t)(c * 128 + bh) * 64 + jbase;
#pragma unroll
        for (int jj = 0; jj < 8; ++jj) sstart[(cb + jj) * 64 + l] = s[jj];
#pragma unroll
        for (int jj = 0; jj < 8; ++jj)
            s[jj] = fmaf(dprod[cb + jj], s[jj], slocal[(cb + jj) * 64 + l]);
    }
#pragma unroll
    for (int jj = 0; jj < 8; ++jj) s_out[sb + (size_t)(jbase + jj) * 64 + l] = s[jj];
}

// pass3: block = (bh, t-chunk), 8 waves = 8 j-chunks; cross-wave LDS reduce
// every 8 steps (ping-pong), wave w stores time-slot w; plain coalesced y.
__launch_bounds__(512) __global__
void wkv_p3(const unsigned short* __restrict__ r, const unsigned short* __restrict__ k,
            const unsigned short* __restrict__ v, const float* __restrict__ d,
            const float* __restrict__ u, const float* __restrict__ sstart,
            float* __restrict__ y)
{
    const int blk = blockIdx.x;
    const int bh = blk & 127;
    const int tc = blk >> 7;
    const int h = bh & 15;
    const int tid = threadIdx.x;
    const int w = tid >> 6;        // wave = j-chunk
    const int l = tid & 63;        // value column i
    const int jbase = w << 3;

    __shared__ float red[2][8][8][64];   // [slot][srcwave][tt][i] = 32 KB

    float s[8];
    const size_t cb = (size_t)(tc * 128 + bh) * 64 + jbase;
#pragma unroll
    for (int jj = 0; jj < 8; ++jj) s[jj] = sstart[(cb + jj) * 64 + l];

    float u8[8];
#pragma unroll
    for (int jj = 0; jj < 8; ++jj) u8[jj] = u[(h << 6) + jbase + jj];

    const size_t base = (size_t)(bh >> 4) * (2048 * 1024) + (size_t)tc * 131072 + (h << 6);
    const unsigned short* rp = r + base + jbase;
    const unsigned short* kp = k + base + jbase;
    const float*          dp = d + base + jbase;
    const unsigned short* vp = v + base + l;
    float*                yp = y + base + l;

    uint4 rA[4], kA[4]; float4 dA[4][2]; unsigned short vA[4];
    uint4 rB[4], kB[4]; float4 dB[4][2]; unsigned short vB[4];

    WKV_LOAD(rA, kA, dA, vA, 0);
    for (int g = 0; g < 16; ++g) {       // 16 groups of 8 steps
        const int t0 = g * 8;
        WKV_LOAD(rB, kB, dB, vB, t0 + 4);
        P3_COMP(rA, kA, dA, vA, g & 1, 0);
        if (g + 1 < 16) WKV_LOAD(rA, kA, dA, vA, t0 + 8);
        P3_COMP(rB, kB, dB, vB, g & 1, 1);
        __syncthreads();
        float acc_ = red[g & 1][0][w][l];
#pragma unroll
        for (int w_ = 1; w_ < 8; ++w_) acc_ += red[g & 1][w_][w][l];
        yp[(size_t)(t0 + w) * 1024] = acc_;
    }
}

// GroupNorm over heads of 64 ch (eps = 1e-5*16), then *g, store bf16 z.
__launch_bounds__(256) __global__
void gn_k(const float* __restrict__ y0,
          const unsigned short* __restrict__ g, const float* __restrict__ gam,
          const float* __restrict__ bet, unsigned short* __restrict__ z)
{
    const int tid = threadIdx.x;
    const size_t row = blockIdx.x;
    const int c0 = tid << 2;
    const size_t idx = row * 1024 + c0;
    const float4 a = *(const float4*)(y0 + idx);
    const float yv0 = a.x, yv1 = a.y, yv2 = a.z, yv3 = a.w;
    float sm = yv0 + yv1 + yv2 + yv3;
    float q = yv0 * yv0 + yv1 * yv1 + yv2 * yv2 + yv3 * yv3;
#pragma unroll
    for (int off = 1; off < 16; off <<= 1) {
        sm += __shfl_xor(sm, off, 64);
        q += __shfl_xor(q, off, 64);
    }
    const float mean = sm * (1.f / 64.f);
    const float var = q * (1.f / 64.f) - mean * mean;
    const float rstd = rsqrtf(var + 1.6e-4f);
    const float4 gm = *(const float4*)(gam + c0);
    const float4 bt = *(const float4*)(bet + c0);
    const ushort4 gg = *(const ushort4*)(g + idx);
    ushort4 o;
    o.x = f2bf(((yv0 - mean) * rstd * gm.x + bt.x) * bf2f(gg.x));
    o.y = f2bf(((yv1 - mean) * rstd * gm.y + bt.y) * bf2f(gg.y));
    o.z = f2bf(((yv2 - mean) * rstd * gm.z + bt.z) * bf2f(gg.z));
    o.w = f2bf(((yv3 - mean) * rstd * gm.w + bt.w) * bf2f(gg.w));
    *(ushort4*)(z + idx) = o;
}

__launch_bounds__(256) __global__
void copy_k(const float4* __restrict__ src, float4* __restrict__ dst)
{
    const size_t i = (size_t)blockIdx.x * 256 + threadIdx.x;
    dst[i] = src[i];
}

}  // namespace

extern "C" void kernel_launch(void* const* d_in, const int* in_sizes, int n_in,
                              void* d_out, int out_size, void* d_ws, size_t ws_size,
                              hipStream_t stream)
{
    (void)in_sizes; (void)n_in; (void)out_size; (void)ws_size;
    const float* x     = (const float*)d_in[0];
    const float* xla   = (const float*)d_in[1];
    const float* s_in  = (const float*)d_in[2];
    const float* mux   = (const float*)d_in[3];
    const float* lam   = (const float*)d_in[4];
    const float* Amat  = (const float*)d_in[5];
    const float* blora = (const float*)d_in[6];
    const float* tdmu  = (const float*)d_in[7];
    const float* tdA   = (const float*)d_in[8];
    const float* tdB   = (const float*)d_in[9];
    const float* u     = (const float*)d_in[10];
    const float* Wk    = (const float*)d_in[11];
    const float* Wv    = (const float*)d_in[12];
    const float* Wr    = (const float*)d_in[13];
    const float* Wo    = (const float*)d_in[14];
    const float* Wg1   = (const float*)d_in[15];
    const float* Wg2   = (const float*)d_in[16];
    const float* gam   = (const float*)d_in[17];
    const float* bet   = (const float*)d_in[18];

    float* out  = (float*)d_out;          // w-scratch until final GEMM
    float* xraw = out + 16777216;         // y0 scratch until final copy
    float* snew = out + 2 * 16777216;

    char* ws = (char*)d_ws;
    unsigned short* mixb   = (unsigned short*)(ws);              // 32 MB (dead after G1 -> slocal)
    unsigned short* xddb   = (unsigned short*)(ws + 33554432);   // 32 MB (dead after f=4 gemm -> sstart)
    unsigned short* t1     = (unsigned short*)(ws + 67108864);   // 5.25 MB (dead after f=4 xdd -> dprod)
    unsigned short* tanh64 = (unsigned short*)(ws + 72351744);   // 2 MB
    unsigned short* tanhg  = (unsigned short*)(ws + 74448896);   // 5.25 MB
    unsigned short* kbuf   = (unsigned short*)(ws + 79691776);   // 32 MB (-> z after wkv)
    unsigned short* vbuf   = (unsigned short*)(ws + 113246208);  // 32 MB
    unsigned short* rbuf   = (unsigned short*)(ws + 146800640);  // 32 MB
    unsigned short* gbuf   = (unsigned short*)(ws + 180355072);  // 32 MB
    unsigned short* wkt    = (unsigned short*)(ws + 213909504);  // 2 MB
    unsigned short* wvt    = (unsigned short*)(ws + 216006656);
    unsigned short* wrt    = (unsigned short*)(ws + 218103808);
    unsigned short* wot    = (unsigned short*)(ws + 220200960);
    unsigned short* at_    = (unsigned short*)(ws + 222298112);  // 256x1024
    unsigned short* tdat   = (unsigned short*)(ws + 222822400);  // 128x1024
    unsigned short* tdbt   = (unsigned short*)(ws + 223084544);  // 1024x64
    unsigned short* wg1t   = (unsigned short*)(ws + 223215616);  // 256x1024
    unsigned short* wg2t   = (unsigned short*)(ws + 223739904);  // 1024x160 (end ~224 MB)

    float* w  = out;            // 16384x1024 fp32 (becomes decay d in-place)
    float* y0 = xraw;           // fp32 y buffer (plain stores, full overwrite)
    float* slocal = (float*)ws;               // 32 MB (over dead mixb)
    float* sstart = (float*)(ws + 33554432);  // 32 MB (over dead xddb)
    float* dprod  = (float*)(ws + 67108864);  // 512 KB (over dead t1)

    // --- weight conversions ---
    convert_k<<<1024, 256, 0, stream>>>(Wk, wkt);
    convert_k<<<1024, 256, 0, stream>>>(Wv, wvt);
    convert_k<<<1024, 256, 0, stream>>>(Wr, wrt);
    convert_k<<<1024, 256, 0, stream>>>(Wo, wot);
    transpose_k<<<dim3(4, 256), 256, 0, stream>>>(Amat, at_, 1024, 160);
    transpose_k<<<dim3(4, 128), 256, 0, stream>>>(tdA, tdat, 1024, 64);
    transpose_k<<<dim3(1, 1024), 256, 0, stream>>>(tdB, tdbt, 64, 1024);
    transpose_k<<<dim3(4, 256), 256, 0, stream>>>(Wg1, wg1t, 1024, 160);
    transpose_k<<<dim3(1, 1024), 256, 0, stream>>>(Wg2, wg2t, 160, 1024);

    // --- G1: t1 = tanh(mix @ A)  (N=160 pad 256, K=1024) ---
    mix_k<<<16384, 256, 0, stream>>>(x, xla, mux, mixb);
    gemm_mfma<ACT_TANH, EPI_NONE, 1><<<dim3(2, 128), 256, 0, stream>>>(
        256, 1024, 160, 160, mixb, at_, nullptr, t1, nullptr);

    // --- f=0: w = tdmu + tanh(w0 @ tdA) @ tdB ---
    xdd_k<<<4096, 256, 0, stream>>>(x, xla, t1, blora, lam, xddb, 0);
    gemm_mfma<ACT_TANH, EPI_NONE, 1><<<dim3(1, 128), 256, 0, stream>>>(
        128, 1024, 64, 64, xddb, tdat, nullptr, tanh64, nullptr);
    gemm_mfma<ACT_NONE, EPI_ADDVEC, 0><<<dim3(8, 128), 256, 0, stream>>>(
        1024, 64, 1024, 1024, tanh64, tdbt, w, nullptr, tdmu);

    // --- f=1: k = (k0 @ Wk^T) * exp(min(w,0)) -> bf16 ---
    xdd_k<<<4096, 256, 0, stream>>>(x, xla, t1, blora, lam, xddb, 1);
    gemm_mfma<ACT_NONE, EPI_KSCALE, 1><<<dim3(8, 128), 256, 0, stream>>>(
        1024, 1024, 1024, 1024, xddb, wkt, nullptr, kbuf, w);

    // --- w -> d = exp(-exp(w)) in place (raw w no longer needed) ---
    decay_k<<<16384, 256, 0, stream>>>(w);

    // --- f=2: v ---
    xdd_k<<<4096, 256, 0, stream>>>(x, xla, t1, blora, lam, xddb, 2);
    gemm_mfma<ACT_NONE, EPI_NONE, 1><<<dim3(8, 128), 256, 0, stream>>>(
        1024, 1024, 1024, 1024, xddb, wvt, nullptr, vbuf, nullptr);

    // --- f=3: r ---
    xdd_k<<<4096, 256, 0, stream>>>(x, xla, t1, blora, lam, xddb, 3);
    gemm_mfma<ACT_NONE, EPI_NONE, 1><<<dim3(8, 128), 256, 0, stream>>>(
        1024, 1024, 1024, 1024, xddb, wrt, nullptr, rbuf, nullptr);

    // --- f=4: g = tanh(g0 @ Wg1) @ Wg2 ---
    xdd_k<<<4096, 256, 0, stream>>>(x, xla, t1, blora, lam, xddb, 4);
    gemm_mfma<ACT_TANH, EPI_NONE, 1><<<dim3(2, 128), 256, 0, stream>>>(
        256, 1024, 160, 160, xddb, wg1t, nullptr, tanhg, nullptr);
    gemm_mfma<ACT_NONE, EPI_NONE, 1><<<dim3(8, 128), 256, 0, stream>>>(
        1024, 160, 1024, 1024, tanhg, wg2t, nullptr, gbuf, nullptr);

    // --- WKV scan: chunked-parallel over T (16 chunks x 128 steps) ---
    wkv_p1<<<16384, 64, 0, stream>>>(kbuf, vbuf, w, slocal);
    dprod_k<<<2048, 64, 0, stream>>>(w, dprod);
    wkv_p2<<<1024, 64, 0, stream>>>(s_in, slocal, dprod, sstart, snew);
    wkv_p3<<<2048, 512, 0, stream>>>(rbuf, kbuf, vbuf, w, u, sstart, y0);

    // --- GroupNorm(y0)*g -> z (reuses kbuf) ---
    gn_k<<<16384, 256, 0, stream>>>(y0, gbuf, gam, bet, kbuf);

    // --- out = z @ Wo^T (fp32, overwrites w scratch) ---
    gemm_mfma<ACT_NONE, EPI_NONE, 0><<<dim3(8, 128), 256, 0, stream>>>(
        1024, 1024, 1024, 1024, kbuf, wot, out, nullptr, nullptr);

    // --- x_raw = x ---
    copy_k<<<16384, 256, 0, stream>>>((const float4*)x, (float4*)xraw);
}